// Round 19
// baseline (406.877 us; speedup 1.0000x reference)
//
#include <hip/hip_runtime.h>

#define NREL   50
#define NBASE  30
#define HID    16
#define NCLS   8

#define SHIFT   9
#define BWID    (1 << SHIFT)       // 512 nodes per bucket
#define NBUKMAX 512                // supports N <= 262144
#define TILE    4096               // edges per scatter block
#define EPB     16                 // edges per thread (256 threads)
#define W2T     56                 // padded t-stride for w2 LDS
#define C1P     36                 // padded comp1 row (floats; 144B rotates banks)
#define SRCB   32                  // srcs per layer1A block

typedef float    vf4 __attribute__((ext_vector_type(4)));
typedef _Float16 vh8 __attribute__((ext_vector_type(8)));

// ---------------- setup ----------------

__global__ void compute_w2_kernel(const float* __restrict__ comp2,
                                  const float* __restrict__ basis2,
                                  float* __restrict__ w2) {
    int i = blockIdx.x * blockDim.x + threadIdx.x;
    if (i >= NREL * HID * NCLS) return;
    int r  = i / (HID * NCLS);
    int hc = i % (HID * NCLS);
    float acc = 0.f;
    #pragma unroll
    for (int b = 0; b < NBASE; ++b)
        acc += comp2[r * NBASE + b] * basis2[b * HID * NCLS + hc];
    w2[i] = acc;
}

// ---------------- bucket histograms (LDS-privatized) ----------------

__global__ void ghist_kernel(const int* __restrict__ src,
                             const int* __restrict__ dst,
                             int* __restrict__ hs, int* __restrict__ hd,
                             int E, int nbuk) {
    __shared__ int lhs[NBUKMAX], lhd[NBUKMAX];
    for (int j = threadIdx.x; j < nbuk; j += blockDim.x) { lhs[j] = 0; lhd[j] = 0; }
    __syncthreads();
    for (long e = (long)blockIdx.x * blockDim.x + threadIdx.x; e < E;
         e += (long)gridDim.x * blockDim.x) {
        atomicAdd(&lhs[src[e] >> SHIFT], 1);
        atomicAdd(&lhd[dst[e] >> SHIFT], 1);
    }
    __syncthreads();
    for (int j = threadIdx.x; j < nbuk; j += blockDim.x) {
        if (lhs[j]) atomicAdd(&hs[j], lhs[j]);
        if (lhd[j]) atomicAdd(&hd[j], lhd[j]);
    }
}

// exclusive scans of both histograms; keeps pristine bases for pass1b/pass3
__global__ void scanbuk_kernel(const int* __restrict__ hs, const int* __restrict__ hd,
                               int* __restrict__ gcs, int* __restrict__ bases_s,
                               int* __restrict__ based, int* __restrict__ gcd,
                               int nbuk, int E) {
    __shared__ int a[NBUKMAX], b[NBUKMAX];
    int tid = threadIdx.x;
    for (int j = tid; j < nbuk; j += blockDim.x) { a[j] = hs[j]; b[j] = hd[j]; }
    __syncthreads();
    if (tid == 0) {
        int run = 0;
        for (int i = 0; i < nbuk; ++i) { int v = a[i]; a[i] = run; run += v; }
        run = 0;
        for (int i = 0; i < nbuk; ++i) { int v = b[i]; b[i] = run; run += v; }
    }
    __syncthreads();
    for (int j = tid; j < nbuk; j += blockDim.x) {
        gcs[j] = a[j]; bases_s[j] = a[j];
        based[j] = b[j]; gcd[j] = b[j];
    }
    if (tid == 0) { bases_s[nbuk] = E; based[nbuk] = E; }
}

// ---------------- pass 1: coarse bucket-sort by src>>SHIFT ----------------
__global__ void pass1_kernel(const int* __restrict__ src,
                             const int* __restrict__ dst,
                             const int* __restrict__ et,
                             int* __restrict__ gcur,
                             int* __restrict__ Ax0, int* __restrict__ Ad0, int E) {
    __shared__ int lhist[NBUKMAX], lbase[NBUKMAX], lcur[NBUKMAX];
    int tid = threadIdx.x;
    for (int j = tid; j < NBUKMAX; j += 256) { lhist[j] = 0; lcur[j] = 0; }
    __syncthreads();
    int px[EPB], pd[EPB]; int bk[EPB];
    long e0 = (long)blockIdx.x * TILE;
    #pragma unroll
    for (int j = 0; j < EPB; ++j) {
        long e = e0 + j * 256 + tid;
        if (e < E) {
            int s = src[e], d = dst[e], t = et[e];
            px[j] = s | (t << 17);
            pd[j] = d;
            bk[j] = s >> SHIFT;
            atomicAdd(&lhist[bk[j]], 1);
        } else bk[j] = -1;
    }
    __syncthreads();
    for (int j = tid; j < NBUKMAX; j += 256)
        if (lhist[j] > 0) lbase[j] = atomicAdd(&gcur[j], lhist[j]);
    __syncthreads();
    #pragma unroll
    for (int j = 0; j < EPB; ++j) {
        if (bk[j] >= 0) {
            int r = atomicAdd(&lcur[bk[j]], 1);
            int pos = lbase[bk[j]] + r;
            Ax0[pos] = px[j];
            Ad0[pos] = pd[j];
        }
    }
}

// ---------------- pass 1b: exact src grouping within each bucket ----------------
__global__ void pass1b_kernel(const int* __restrict__ Ax0,
                              const int* __restrict__ Ad0,
                              const int* __restrict__ bases_s,
                              int* __restrict__ Ax, int* __restrict__ Ad,
                              int* __restrict__ rowptr_s, int N, int E) {
    __shared__ int lh[BWID], sA[BWID], sB[BWID];
    int blk = blockIdx.x, tid = threadIdx.x;
    int k0 = bases_s[blk], k1 = bases_s[blk + 1], cnt = k1 - k0;
    for (int j = tid; j < BWID; j += 256) lh[j] = 0;
    __syncthreads();
    for (int i = tid; i < cnt; i += 256) {
        int slow = Ax0[k0 + i] & (BWID - 1);
        atomicAdd(&lh[slow], 1);
    }
    __syncthreads();
    for (int j = tid; j < BWID; j += 256) sA[j] = lh[j];
    __syncthreads();
    int* cur = sA; int* oth = sB;
    for (int off = 1; off < BWID; off <<= 1) {
        for (int j = tid; j < BWID; j += 256)
            oth[j] = cur[j] + (j >= off ? cur[j - off] : 0);
        __syncthreads();
        int* t_ = cur; cur = oth; oth = t_;
    }
    for (int j = tid; j < BWID; j += 256) {
        int excl = cur[j] - lh[j];
        oth[j] = excl;
        int s = blk * BWID + j;
        if (s < N) rowptr_s[s] = k0 + excl;
    }
    __syncthreads();
    for (int i = tid; i < cnt; i += 256) {
        int x = Ax0[k0 + i], d = Ad0[k0 + i];
        int slow = x & (BWID - 1);
        int pos = atomicAdd(&oth[slow], 1);
        Ax[k0 + pos] = x;
        Ad[k0 + pos] = d;
    }
    if (blk == 0 && tid == 0) rowptr_s[N] = E;
}

// ---------------- pass 2: bucket-sort by dst>>SHIFT ----------------
// B[pos] = {s|t<<17, psi | dlow<<21}, psi = index into Ax (= msg row).
__global__ void pass2_kernel(const int* __restrict__ Ax,
                             const int* __restrict__ Ad,
                             int* __restrict__ gcur, int2* __restrict__ B, int E) {
    __shared__ int lhist[NBUKMAX], lbase[NBUKMAX], lcur[NBUKMAX];
    int tid = threadIdx.x;
    for (int j = tid; j < NBUKMAX; j += 256) { lhist[j] = 0; lcur[j] = 0; }
    __syncthreads();
    int2 p[EPB]; int bk[EPB];
    long e0 = (long)blockIdx.x * TILE;
    #pragma unroll
    for (int j = 0; j < EPB; ++j) {
        long e = e0 + j * 256 + tid;
        if (e < E) {
            int x = Ax[e];
            int d = Ad[e];
            p[j] = make_int2(x, (int)e | ((d & (BWID - 1)) << 21));
            bk[j] = d >> SHIFT;
            atomicAdd(&lhist[bk[j]], 1);
        } else bk[j] = -1;
    }
    __syncthreads();
    for (int j = tid; j < NBUKMAX; j += 256)
        if (lhist[j] > 0) lbase[j] = atomicAdd(&gcur[j], lhist[j]);
    __syncthreads();
    #pragma unroll
    for (int j = 0; j < EPB; ++j) {
        if (bk[j] >= 0) {
            int r = atomicAdd(&lcur[bk[j]], 1);
            B[lbase[bk[j]] + r] = p[j];
        }
    }
}

// ---------------- pass 3: exact dst grouping within each bucket ----------------
__global__ void pass3_kernel(const int2* __restrict__ B,
                             const int* __restrict__ based,
                             int2* __restrict__ e2, int* __restrict__ rowptr,
                             int N, int E) {
    __shared__ int lh[BWID], sA[BWID], sB[BWID];
    int blk = blockIdx.x, tid = threadIdx.x;
    int k0 = based[blk], k1 = based[blk + 1], cnt = k1 - k0;
    for (int j = tid; j < BWID; j += 256) lh[j] = 0;
    __syncthreads();
    for (int i = tid; i < cnt; i += 256) {
        int dlow = ((unsigned)B[k0 + i].y) >> 21;
        atomicAdd(&lh[dlow], 1);
    }
    __syncthreads();
    for (int j = tid; j < BWID; j += 256) sA[j] = lh[j];
    __syncthreads();
    int* cur = sA; int* oth = sB;
    for (int off = 1; off < BWID; off <<= 1) {
        for (int j = tid; j < BWID; j += 256)
            oth[j] = cur[j] + (j >= off ? cur[j - off] : 0);
        __syncthreads();
        int* t_ = cur; cur = oth; oth = t_;
    }
    for (int j = tid; j < BWID; j += 256) {
        int excl = cur[j] - lh[j];
        oth[j] = excl;
        int d = blk * BWID + j;
        if (d < N) rowptr[d] = k0 + excl;
    }
    __syncthreads();
    for (int i = tid; i < cnt; i += 256) {
        int2 b = B[k0 + i];
        int dlow = ((unsigned)b.y) >> 21;
        int pos = atomicAdd(&oth[dlow], 1);
        e2[k0 + pos] = make_int2(b.x, b.y & 0x1FFFFF);
    }
    if (blk == 0 && tid == 0) rowptr[N] = E;
}

// ---------------- layer 1 phase A: LDS-staged basis tile (32 srcs/block) ----------------
// Staging reads are contiguous 2KB runs per b-plane (page-friendly streaming);
// compute = R17's int4-batch VALU loop reading basis from LDS.
// bst layout mirrors the b-plane order: bst[b][ss][ch] (fp16) -> staging writes
// are fully coalesced & conflict-free; per-lane reads are 2 lanes/bank (free).
__global__ void layer1A_lds_kernel(const int* __restrict__ Ax,
                                   const int* __restrict__ rowptr_s,
                                   const float* __restrict__ comp1,
                                   const float* __restrict__ basis1,
                                   _Float16* __restrict__ msg, int N) {
    __shared__ float c1s[NREL * C1P];                  // 7.2 KB
    __shared__ _Float16 bst[NBASE * SRCB * HID];       // 30 KB
    int tid = threadIdx.x;
    for (int i = tid; i < NREL * C1P; i += 256) {
        int t = i / C1P, b = i % C1P;
        c1s[i] = (b < NBASE) ? comp1[t * NBASE + b] : 0.f;
    }
    int s0 = blockIdx.x * SRCB;
    {
        // stage: element i = b*(SRCB*HID) + ss*HID + ch ; global reads are
        // 2KB-contiguous per b-plane, consecutive blocks read adjacent 2KB.
        const int PL = SRCB * HID;                     // 512
        int nv = (s0 + SRCB <= N) ? NBASE * PL : 0;    // fast path full tile
        if (nv) {
            const float* gp = basis1 + (long)s0 * HID; // plane offset added per-b
            for (int i = tid; i < NBASE * PL; i += 256) {
                int b = i >> 9;
                int r = i & (PL - 1);
                bst[i] = (_Float16)gp[(long)b * N * HID + r];
            }
        } else {
            for (int i = tid; i < NBASE * PL; i += 256) {
                int b = i >> 9;
                int r = i & (PL - 1);
                int sg = s0 + (r >> 4);
                float v = (sg < N) ? basis1[((long)b * N + sg) * HID + (r & 15)] : 0.f;
                bst[i] = (_Float16)v;
            }
        }
    }
    __syncthreads();

    int gid = tid >> 4;        // src-group 0..15
    int l   = tid & 15;        // channel

    #pragma unroll
    for (int rep = 0; rep < SRCB / 16; ++rep) {
        int ss = rep * 16 + gid;
        int s = s0 + ss;
        if (s >= N) continue;
        int k0 = rowptr_s[s], k1 = rowptr_s[s + 1];
        if (k0 == k1) continue;

        vf4 b4[8];
        {
            float breg[32];
            #pragma unroll
            for (int b = 0; b < NBASE; ++b)
                breg[b] = (float)bst[b * (SRCB * HID) + ss * HID + l];
            breg[30] = 0.f; breg[31] = 0.f;
            #pragma unroll
            for (int i = 0; i < 8; ++i)
                b4[i] = (vf4){breg[4*i], breg[4*i+1], breg[4*i+2], breg[4*i+3]};
        }

        int k = k0;
        int kalign = (k0 + 3) & ~3;
        for (; k < k1 && k < kalign; ++k) {
            int t = ((unsigned)Ax[k]) >> 17;
            const vf4* cr4 = reinterpret_cast<const vf4*>(c1s + t * C1P);
            vf4 acc4 = {0.f, 0.f, 0.f, 0.f};
            #pragma unroll
            for (int i = 0; i < 8; ++i)
                acc4 += cr4[i] * b4[i];
            float acc = (acc4.x + acc4.y) + (acc4.z + acc4.w);
            __builtin_nontemporal_store((_Float16)acc, &msg[(long)k * HID + l]);
        }
        if (k + 4 <= k1) {
            int4 cx = *reinterpret_cast<const int4*>(Ax + k);
            for (;;) {
                bool more = (k + 8 <= k1);
                int4 nx;
                if (more) nx = *reinterpret_cast<const int4*>(Ax + k + 4);
                const vf4* c0 = reinterpret_cast<const vf4*>(c1s + (((unsigned)cx.x) >> 17) * C1P);
                const vf4* c1 = reinterpret_cast<const vf4*>(c1s + (((unsigned)cx.y) >> 17) * C1P);
                const vf4* c2 = reinterpret_cast<const vf4*>(c1s + (((unsigned)cx.z) >> 17) * C1P);
                const vf4* c3 = reinterpret_cast<const vf4*>(c1s + (((unsigned)cx.w) >> 17) * C1P);
                vf4 a0 = {0.f,0.f,0.f,0.f}, a1 = a0, a2 = a0, a3 = a0;
                #pragma unroll
                for (int i = 0; i < 8; ++i) {
                    a0 += c0[i] * b4[i];
                    a1 += c1[i] * b4[i];
                    a2 += c2[i] * b4[i];
                    a3 += c3[i] * b4[i];
                }
                float r0 = (a0.x + a0.y) + (a0.z + a0.w);
                float r1 = (a1.x + a1.y) + (a1.z + a1.w);
                float r2 = (a2.x + a2.y) + (a2.z + a2.w);
                float r3 = (a3.x + a3.y) + (a3.z + a3.w);
                __builtin_nontemporal_store((_Float16)r0, &msg[(long)(k + 0) * HID + l]);
                __builtin_nontemporal_store((_Float16)r1, &msg[(long)(k + 1) * HID + l]);
                __builtin_nontemporal_store((_Float16)r2, &msg[(long)(k + 2) * HID + l]);
                __builtin_nontemporal_store((_Float16)r3, &msg[(long)(k + 3) * HID + l]);
                k += 4;
                if (!more) break;
                cx = nx;
            }
        }
        for (; k < k1; ++k) {
            int t = ((unsigned)Ax[k]) >> 17;
            const vf4* cr4 = reinterpret_cast<const vf4*>(c1s + t * C1P);
            vf4 acc4 = {0.f, 0.f, 0.f, 0.f};
            #pragma unroll
            for (int i = 0; i < 8; ++i)
                acc4 += cr4[i] * b4[i];
            float acc = (acc4.x + acc4.y) + (acc4.z + acc4.w);
            __builtin_nontemporal_store((_Float16)acc, &msg[(long)k * HID + l]);
        }
    }
}

// ---------------- layer 1 phase B: 8 threads per dst node, fp16 msg gather, fp16 h out ----------------
__global__ void layer1B_kernel(const int2* __restrict__ e2,
                               const int* __restrict__ rowptr,
                               const _Float16* __restrict__ msg,
                               const float* __restrict__ root1,
                               const float* __restrict__ bias1,
                               _Float16* __restrict__ h, float* __restrict__ sinv, int N) {
    long gid = (long)blockIdx.x * blockDim.x + threadIdx.x;
    int d = (int)(gid >> 3);
    if (d >= N) return;
    int q = (int)(gid & 7);
    int k0 = rowptr[d], k1 = rowptr[d + 1];

    float acc[HID];
    #pragma unroll
    for (int i = 0; i < HID; ++i) acc[i] = 0.f;

    for (int k = k0 + q; k < k1; k += 8) {
        int2 v = e2[k];
        unsigned t = ((unsigned)v.x) >> 17;
        int c = 0;
        for (int j = k0; j < k1; ++j)
            c += ((((unsigned)e2[j].x) >> 17) == t);
        float inv = 1.0f / (float)c;
        sinv[k] = inv;
        const vh8* m8 = reinterpret_cast<const vh8*>(msg + (long)v.y * HID);
        vh8 m0 = __builtin_nontemporal_load(m8);
        vh8 m1 = __builtin_nontemporal_load(m8 + 1);
        #pragma unroll
        for (int i = 0; i < 8; ++i) {
            acc[i]     += inv * (float)m0[i];
            acc[i + 8] += inv * (float)m1[i];
        }
    }

    #pragma unroll
    for (int i = 0; i < HID; ++i) {
        acc[i] += __shfl_xor(acc[i], 1);
        acc[i] += __shfl_xor(acc[i], 2);
        acc[i] += __shfl_xor(acc[i], 4);
    }

    if (q == 0) {
        vh8 o0, o1;
        #pragma unroll
        for (int i = 0; i < 8; ++i) {
            o0[i] = (_Float16)(acc[i]     + root1[(size_t)d * HID + i]     + bias1[i]);
            o1[i] = (_Float16)(acc[i + 8] + root1[(size_t)d * HID + i + 8] + bias1[i + 8]);
        }
        vh8* h8 = reinterpret_cast<vh8*>(h + (size_t)d * HID);
        h8[0] = o0;
        h8[1] = o1;
    }
}

// ---------------- layer 2: 8 threads per dst node (k-split), fp16 h ----------------
__global__ void layer2_kernel(const int2* __restrict__ e2,
                              const int* __restrict__ rowptr,
                              const float* __restrict__ sinv,
                              const float* __restrict__ w2,
                              const _Float16* __restrict__ h,
                              const float* __restrict__ root2,
                              const float* __restrict__ bias2,
                              float* __restrict__ out, int N) {
    __shared__ float w2s[HID * NCLS * W2T];
    for (int i = threadIdx.x; i < NREL * HID * NCLS; i += blockDim.x) {
        int t = i / (HID * NCLS);
        int hc = i % (HID * NCLS);
        w2s[hc * W2T + t] = w2[i];
    }
    __syncthreads();

    long gid = (long)blockIdx.x * blockDim.x + threadIdx.x;
    int d = (int)(gid >> 3);
    if (d >= N) return;
    int q = (int)(gid & 7);
    int k0 = rowptr[d], k1 = rowptr[d + 1];

    float acc[NCLS];
    #pragma unroll
    for (int c = 0; c < NCLS; ++c) acc[c] = 0.f;

    for (int k = k0 + q; k < k1; k += 8) {
        int2 v = e2[k];
        int s = v.x & 0x1FFFF;
        int t = ((unsigned)v.x) >> 17;
        float inv = sinv[k];
        const vh8* h8 = reinterpret_cast<const vh8*>(h + (size_t)s * HID);
        vh8 m0 = h8[0];
        vh8 m1 = h8[1];
        float hv[HID];
        #pragma unroll
        for (int i = 0; i < 8; ++i) { hv[i] = (float)m0[i]; hv[i + 8] = (float)m1[i]; }
        float tmp[NCLS];
        #pragma unroll
        for (int c = 0; c < NCLS; ++c) tmp[c] = 0.f;
        #pragma unroll
        for (int i = 0; i < HID; ++i) {
            #pragma unroll
            for (int c = 0; c < NCLS; ++c)
                tmp[c] += hv[i] * w2s[(i * NCLS + c) * W2T + t];
        }
        #pragma unroll
        for (int c = 0; c < NCLS; ++c) acc[c] += inv * tmp[c];
    }

    #pragma unroll
    for (int c = 0; c < NCLS; ++c) {
        acc[c] += __shfl_xor(acc[c], 1);
        acc[c] += __shfl_xor(acc[c], 2);
        acc[c] += __shfl_xor(acc[c], 4);
    }

    if (q == 0) {
        const vh8* h8 = reinterpret_cast<const vh8*>(h + (size_t)d * HID);
        vh8 m0 = h8[0];
        vh8 m1 = h8[1];
        float hv[HID];
        #pragma unroll
        for (int i = 0; i < 8; ++i) { hv[i] = (float)m0[i]; hv[i + 8] = (float)m1[i]; }
        #pragma unroll
        for (int i = 0; i < HID; ++i) {
            #pragma unroll
            for (int c = 0; c < NCLS; ++c)
                acc[c] += hv[i] * root2[i * NCLS + c];
        }
        #pragma unroll
        for (int c = 0; c < NCLS; ++c) acc[c] += bias2[c];
        float4* o4 = reinterpret_cast<float4*>(out + (size_t)d * NCLS);
        o4[0] = make_float4(acc[0], acc[1], acc[2], acc[3]);
        o4[1] = make_float4(acc[4], acc[5], acc[6], acc[7]);
    }
}

// ---------------- launch ----------------

extern "C" void kernel_launch(void* const* d_in, const int* in_sizes, int n_in,
                              void* d_out, int out_size, void* d_ws, size_t ws_size,
                              hipStream_t stream) {
    const int*   edge_index = (const int*)  d_in[0];
    const int*   edge_type  = (const int*)  d_in[1];
    const float* basis1     = (const float*)d_in[2];
    const float* comp1      = (const float*)d_in[3];
    const float* root1      = (const float*)d_in[4];
    const float* bias1      = (const float*)d_in[5];
    const float* basis2     = (const float*)d_in[6];
    const float* comp2      = (const float*)d_in[7];
    const float* root2      = (const float*)d_in[8];
    const float* bias2      = (const float*)d_in[9];
    float* out = (float*)d_out;

    const int E = in_sizes[1];
    const int N = in_sizes[4] / HID;
    const int nbuk = (N + BWID - 1) >> SHIFT;
    const int* src = edge_index;
    const int* dst = edge_index + E;

    char* base = (char*)d_ws;
    size_t off = 0;
    auto alloc = [&](size_t bytes, size_t align) -> char* {
        off = (off + align - 1) & ~(align - 1);
        char* p = base + off;
        off += bytes;
        return p;
    };
    // contiguous zero region: hs | hd
    int*  hs       = (int*)  alloc((size_t)NBUKMAX * 4, 4);
    int*  hd       = (int*)  alloc((size_t)NBUKMAX * 4, 4);
    int*  gcs      = (int*)  alloc((size_t)NBUKMAX * 4, 4);
    int*  gcd      = (int*)  alloc((size_t)NBUKMAX * 4, 4);
    int*  bases_s  = (int*)  alloc((size_t)(NBUKMAX + 1) * 4, 4);
    int*  based    = (int*)  alloc((size_t)(NBUKMAX + 1) * 4, 4);
    int*  rowptr   = (int*)  alloc((size_t)(N + 1) * 4, 4);
    int*  rowptr_s = (int*)  alloc((size_t)(N + 1) * 4, 4);
    float* w2      = (float*)alloc((size_t)NREL * HID * NCLS * 4, 16);
    _Float16* h    = (_Float16*)alloc((size_t)N * HID * 2, 16);
    float* sinv    = (float*)alloc((size_t)E * 4, 4);
    int*  Ax0      = (int*)  alloc((size_t)E * 4, 4);
    int*  Ad0      = (int*)  alloc((size_t)E * 4, 4);
    int*  Ax       = (int*)  alloc((size_t)E * 4, 16);
    int*  Ad       = (int*)  alloc((size_t)E * 4, 4);
    int2* B        = (int2*) alloc((size_t)E * 8, 8);
    int2* e2       = (int2*) alloc((size_t)E * 8, 8);
    _Float16* msg  = (_Float16*)alloc((size_t)E * HID * 2, 16);

    hipMemsetAsync(hs, 0, (size_t)NBUKMAX * 2 * 4, stream);

    {   int M = NREL * HID * NCLS;
        compute_w2_kernel<<<(M + 255) / 256, 256, 0, stream>>>(comp2, basis2, w2);
    }
    ghist_kernel<<<2048, 256, 0, stream>>>(src, dst, hs, hd, E, nbuk);
    scanbuk_kernel<<<1, 256, 0, stream>>>(hs, hd, gcs, bases_s, based, gcd, nbuk, E);

    int nblk = (E + TILE - 1) / TILE;
    pass1_kernel<<<nblk, 256, 0, stream>>>(src, dst, edge_type, gcs, Ax0, Ad0, E);
    pass1b_kernel<<<nbuk, 256, 0, stream>>>(Ax0, Ad0, bases_s, Ax, Ad, rowptr_s, N, E);
    pass2_kernel<<<nblk, 256, 0, stream>>>(Ax, Ad, gcd, B, E);
    pass3_kernel<<<nbuk, 256, 0, stream>>>(B, based, e2, rowptr, N, E);

    {   int blocks = (N + SRCB - 1) / SRCB;
        layer1A_lds_kernel<<<blocks, 256, 0, stream>>>(
            Ax, rowptr_s, comp1, basis1, msg, N);
    }
    {   long total = (long)N * 8;
        layer1B_kernel<<<(int)((total + 255) / 256), 256, 0, stream>>>(
            e2, rowptr, msg, root1, bias1, h, sinv, N);
    }
    {   long total = (long)N * 8;
        layer2_kernel<<<(int)((total + 255) / 256), 256, 0, stream>>>(
            e2, rowptr, sinv, w2, h, root2, bias2, out, N);
    }
}

// Round 20
// 361.720 us; speedup vs baseline: 1.1248x; 1.1248x over previous
//
#include <hip/hip_runtime.h>

#define NREL   50
#define NBASE  30
#define HID    16
#define NCLS   8

#define SHIFT   9
#define BWID    (1 << SHIFT)       // 512 nodes per bucket
#define NBUKMAX 512                // supports N <= 262144
#define TILE    4096               // edges per scatter block
#define EPB     16                 // edges per thread (256 threads)
#define W2P     132                // padded w2 row (floats), 528B 16B-aligned
#define C1P     36                 // padded comp1 row (floats; 144B rotates banks)

typedef float    vf4 __attribute__((ext_vector_type(4)));
typedef _Float16 vh8 __attribute__((ext_vector_type(8)));

// ---------------- setup ----------------

__global__ void compute_w2_kernel(const float* __restrict__ comp2,
                                  const float* __restrict__ basis2,
                                  float* __restrict__ w2) {
    int i = blockIdx.x * blockDim.x + threadIdx.x;
    if (i >= NREL * HID * NCLS) return;
    int r  = i / (HID * NCLS);
    int hc = i % (HID * NCLS);
    float acc = 0.f;
    #pragma unroll
    for (int b = 0; b < NBASE; ++b)
        acc += comp2[r * NBASE + b] * basis2[b * HID * NCLS + hc];
    w2[i] = acc;
}

// ---------------- bucket histograms (LDS-privatized) ----------------

__global__ void ghist_kernel(const int* __restrict__ src,
                             const int* __restrict__ dst,
                             int* __restrict__ hs, int* __restrict__ hd,
                             int E, int nbuk) {
    __shared__ int lhs[NBUKMAX], lhd[NBUKMAX];
    for (int j = threadIdx.x; j < nbuk; j += blockDim.x) { lhs[j] = 0; lhd[j] = 0; }
    __syncthreads();
    for (long e = (long)blockIdx.x * blockDim.x + threadIdx.x; e < E;
         e += (long)gridDim.x * blockDim.x) {
        atomicAdd(&lhs[src[e] >> SHIFT], 1);
        atomicAdd(&lhd[dst[e] >> SHIFT], 1);
    }
    __syncthreads();
    for (int j = threadIdx.x; j < nbuk; j += blockDim.x) {
        if (lhs[j]) atomicAdd(&hs[j], lhs[j]);
        if (lhd[j]) atomicAdd(&hd[j], lhd[j]);
    }
}

// exclusive scans of both histograms; keeps pristine bases for pass1b/pass3
__global__ void scanbuk_kernel(const int* __restrict__ hs, const int* __restrict__ hd,
                               int* __restrict__ gcs, int* __restrict__ bases_s,
                               int* __restrict__ based, int* __restrict__ gcd,
                               int nbuk, int E) {
    __shared__ int a[NBUKMAX], b[NBUKMAX];
    int tid = threadIdx.x;
    for (int j = tid; j < nbuk; j += blockDim.x) { a[j] = hs[j]; b[j] = hd[j]; }
    __syncthreads();
    if (tid == 0) {
        int run = 0;
        for (int i = 0; i < nbuk; ++i) { int v = a[i]; a[i] = run; run += v; }
        run = 0;
        for (int i = 0; i < nbuk; ++i) { int v = b[i]; b[i] = run; run += v; }
    }
    __syncthreads();
    for (int j = tid; j < nbuk; j += blockDim.x) {
        gcs[j] = a[j]; bases_s[j] = a[j];
        based[j] = b[j]; gcd[j] = b[j];
    }
    if (tid == 0) { bases_s[nbuk] = E; based[nbuk] = E; }
}

// ---------------- pass 1: coarse bucket-sort by src>>SHIFT ----------------
__global__ void pass1_kernel(const int* __restrict__ src,
                             const int* __restrict__ dst,
                             const int* __restrict__ et,
                             int* __restrict__ gcur,
                             int* __restrict__ Ax0, int* __restrict__ Ad0, int E) {
    __shared__ int lhist[NBUKMAX], lbase[NBUKMAX], lcur[NBUKMAX];
    int tid = threadIdx.x;
    for (int j = tid; j < NBUKMAX; j += 256) { lhist[j] = 0; lcur[j] = 0; }
    __syncthreads();
    int px[EPB], pd[EPB]; int bk[EPB];
    long e0 = (long)blockIdx.x * TILE;
    #pragma unroll
    for (int j = 0; j < EPB; ++j) {
        long e = e0 + j * 256 + tid;
        if (e < E) {
            int s = src[e], d = dst[e], t = et[e];
            px[j] = s | (t << 17);
            pd[j] = d;
            bk[j] = s >> SHIFT;
            atomicAdd(&lhist[bk[j]], 1);
        } else bk[j] = -1;
    }
    __syncthreads();
    for (int j = tid; j < NBUKMAX; j += 256)
        if (lhist[j] > 0) lbase[j] = atomicAdd(&gcur[j], lhist[j]);
    __syncthreads();
    #pragma unroll
    for (int j = 0; j < EPB; ++j) {
        if (bk[j] >= 0) {
            int r = atomicAdd(&lcur[bk[j]], 1);
            int pos = lbase[bk[j]] + r;
            Ax0[pos] = px[j];
            Ad0[pos] = pd[j];
        }
    }
}

// ---------------- pass 1b: exact src grouping within each bucket ----------------
__global__ void pass1b_kernel(const int* __restrict__ Ax0,
                              const int* __restrict__ Ad0,
                              const int* __restrict__ bases_s,
                              int* __restrict__ Ax, int* __restrict__ Ad,
                              int* __restrict__ rowptr_s, int N, int E) {
    __shared__ int lh[BWID], sA[BWID], sB[BWID];
    int blk = blockIdx.x, tid = threadIdx.x;
    int k0 = bases_s[blk], k1 = bases_s[blk + 1], cnt = k1 - k0;
    for (int j = tid; j < BWID; j += 256) lh[j] = 0;
    __syncthreads();
    for (int i = tid; i < cnt; i += 256) {
        int slow = Ax0[k0 + i] & (BWID - 1);
        atomicAdd(&lh[slow], 1);
    }
    __syncthreads();
    for (int j = tid; j < BWID; j += 256) sA[j] = lh[j];
    __syncthreads();
    int* cur = sA; int* oth = sB;
    for (int off = 1; off < BWID; off <<= 1) {
        for (int j = tid; j < BWID; j += 256)
            oth[j] = cur[j] + (j >= off ? cur[j - off] : 0);
        __syncthreads();
        int* t_ = cur; cur = oth; oth = t_;
    }
    for (int j = tid; j < BWID; j += 256) {
        int excl = cur[j] - lh[j];
        oth[j] = excl;
        int s = blk * BWID + j;
        if (s < N) rowptr_s[s] = k0 + excl;
    }
    __syncthreads();
    for (int i = tid; i < cnt; i += 256) {
        int x = Ax0[k0 + i], d = Ad0[k0 + i];
        int slow = x & (BWID - 1);
        int pos = atomicAdd(&oth[slow], 1);
        Ax[k0 + pos] = x;
        Ad[k0 + pos] = d;
    }
    if (blk == 0 && tid == 0) rowptr_s[N] = E;
}

// ---------------- pass 2: bucket-sort by dst>>SHIFT ----------------
// B[pos] = {s|t<<17, psi | dlow<<21}, psi = index into Ax (= msg row).
__global__ void pass2_kernel(const int* __restrict__ Ax,
                             const int* __restrict__ Ad,
                             int* __restrict__ gcur, int2* __restrict__ B, int E) {
    __shared__ int lhist[NBUKMAX], lbase[NBUKMAX], lcur[NBUKMAX];
    int tid = threadIdx.x;
    for (int j = tid; j < NBUKMAX; j += 256) { lhist[j] = 0; lcur[j] = 0; }
    __syncthreads();
    int2 p[EPB]; int bk[EPB];
    long e0 = (long)blockIdx.x * TILE;
    #pragma unroll
    for (int j = 0; j < EPB; ++j) {
        long e = e0 + j * 256 + tid;
        if (e < E) {
            int x = Ax[e];
            int d = Ad[e];
            p[j] = make_int2(x, (int)e | ((d & (BWID - 1)) << 21));
            bk[j] = d >> SHIFT;
            atomicAdd(&lhist[bk[j]], 1);
        } else bk[j] = -1;
    }
    __syncthreads();
    for (int j = tid; j < NBUKMAX; j += 256)
        if (lhist[j] > 0) lbase[j] = atomicAdd(&gcur[j], lhist[j]);
    __syncthreads();
    #pragma unroll
    for (int j = 0; j < EPB; ++j) {
        if (bk[j] >= 0) {
            int r = atomicAdd(&lcur[bk[j]], 1);
            B[lbase[bk[j]] + r] = p[j];
        }
    }
}

// ---------------- pass 3: exact dst grouping within each bucket ----------------
__global__ void pass3_kernel(const int2* __restrict__ B,
                             const int* __restrict__ based,
                             int2* __restrict__ e2, int* __restrict__ rowptr,
                             int N, int E) {
    __shared__ int lh[BWID], sA[BWID], sB[BWID];
    int blk = blockIdx.x, tid = threadIdx.x;
    int k0 = based[blk], k1 = based[blk + 1], cnt = k1 - k0;
    for (int j = tid; j < BWID; j += 256) lh[j] = 0;
    __syncthreads();
    for (int i = tid; i < cnt; i += 256) {
        int dlow = ((unsigned)B[k0 + i].y) >> 21;
        atomicAdd(&lh[dlow], 1);
    }
    __syncthreads();
    for (int j = tid; j < BWID; j += 256) sA[j] = lh[j];
    __syncthreads();
    int* cur = sA; int* oth = sB;
    for (int off = 1; off < BWID; off <<= 1) {
        for (int j = tid; j < BWID; j += 256)
            oth[j] = cur[j] + (j >= off ? cur[j - off] : 0);
        __syncthreads();
        int* t_ = cur; cur = oth; oth = t_;
    }
    for (int j = tid; j < BWID; j += 256) {
        int excl = cur[j] - lh[j];
        oth[j] = excl;
        int d = blk * BWID + j;
        if (d < N) rowptr[d] = k0 + excl;
    }
    __syncthreads();
    for (int i = tid; i < cnt; i += 256) {
        int2 b = B[k0 + i];
        int dlow = ((unsigned)b.y) >> 21;
        int pos = atomicAdd(&oth[dlow], 1);
        e2[k0 + pos] = make_int2(b.x, b.y & 0x1FFFFF);
    }
    if (blk == 0 && tid == 0) rowptr[N] = E;
}

// ---------------- layer 1 phase A: node-centric, pipelined 4-edge ILP, fp16 msg ----------------
__global__ void layer1A_node_kernel(const int* __restrict__ Ax,
                                    const int* __restrict__ rowptr_s,
                                    const float* __restrict__ comp1,
                                    const float* __restrict__ basis1,
                                    _Float16* __restrict__ msg, int N) {
    __shared__ float c1s[NREL * C1P];
    for (int i = threadIdx.x; i < NREL * C1P; i += blockDim.x) {
        int t = i / C1P, b = i % C1P;
        c1s[i] = (b < NBASE) ? comp1[t * NBASE + b] : 0.f;
    }
    __syncthreads();
    int gid = threadIdx.x >> 4;
    int l   = threadIdx.x & 15;
    int s = blockIdx.x * 16 + gid;
    if (s >= N) return;
    int k0 = rowptr_s[s], k1 = rowptr_s[s + 1];
    if (k0 == k1) return;

    vf4 b4[8];
    {
        long stride = (long)N * HID;
        const float* bp = basis1 + (long)s * HID + l;
        float breg[32];
        #pragma unroll
        for (int b = 0; b < NBASE; ++b)
            breg[b] = bp[(long)b * stride];
        #pragma unroll
        for (int b = NBASE; b < 32; ++b) breg[b] = 0.f;
        #pragma unroll
        for (int i = 0; i < 8; ++i)
            b4[i] = (vf4){breg[4*i], breg[4*i+1], breg[4*i+2], breg[4*i+3]};
    }

    int k = k0;
    if (k + 4 <= k1) {
        int c0x = Ax[k + 0], c1x = Ax[k + 1], c2x = Ax[k + 2], c3x = Ax[k + 3];
        for (;;) {
            bool more = (k + 8 <= k1);
            int n0, n1, n2, n3;
            if (more) {                       // prefetch next batch's records
                n0 = Ax[k + 4]; n1 = Ax[k + 5]; n2 = Ax[k + 6]; n3 = Ax[k + 7];
            }
            const vf4* c0 = reinterpret_cast<const vf4*>(c1s + (((unsigned)c0x) >> 17) * C1P);
            const vf4* c1 = reinterpret_cast<const vf4*>(c1s + (((unsigned)c1x) >> 17) * C1P);
            const vf4* c2 = reinterpret_cast<const vf4*>(c1s + (((unsigned)c2x) >> 17) * C1P);
            const vf4* c3 = reinterpret_cast<const vf4*>(c1s + (((unsigned)c3x) >> 17) * C1P);
            vf4 a0 = {0.f,0.f,0.f,0.f}, a1 = a0, a2 = a0, a3 = a0;
            #pragma unroll
            for (int i = 0; i < 8; ++i) {
                a0 += c0[i] * b4[i];
                a1 += c1[i] * b4[i];
                a2 += c2[i] * b4[i];
                a3 += c3[i] * b4[i];
            }
            float r0 = (a0.x + a0.y) + (a0.z + a0.w);
            float r1 = (a1.x + a1.y) + (a1.z + a1.w);
            float r2 = (a2.x + a2.y) + (a2.z + a2.w);
            float r3 = (a3.x + a3.y) + (a3.z + a3.w);
            __builtin_nontemporal_store((_Float16)r0, &msg[(long)(k + 0) * HID + l]);
            __builtin_nontemporal_store((_Float16)r1, &msg[(long)(k + 1) * HID + l]);
            __builtin_nontemporal_store((_Float16)r2, &msg[(long)(k + 2) * HID + l]);
            __builtin_nontemporal_store((_Float16)r3, &msg[(long)(k + 3) * HID + l]);
            k += 4;
            if (!more) break;
            c0x = n0; c1x = n1; c2x = n2; c3x = n3;
        }
    }
    for (; k < k1; ++k) {
        int t = ((unsigned)Ax[k]) >> 17;
        const vf4* cr4 = reinterpret_cast<const vf4*>(c1s + t * C1P);
        vf4 acc4 = {0.f, 0.f, 0.f, 0.f};
        #pragma unroll
        for (int i = 0; i < 8; ++i)
            acc4 += cr4[i] * b4[i];
        float acc = (acc4.x + acc4.y) + (acc4.z + acc4.w);
        __builtin_nontemporal_store((_Float16)acc, &msg[(long)k * HID + l]);
    }
}

// ---------------- layer 1 phase B: 8 threads per dst node, fp16 msg gather, fp16 h out ----------------
__global__ void layer1B_kernel(const int2* __restrict__ e2,
                               const int* __restrict__ rowptr,
                               const _Float16* __restrict__ msg,
                               const float* __restrict__ root1,
                               const float* __restrict__ bias1,
                               _Float16* __restrict__ h, float* __restrict__ sinv, int N) {
    long gid = (long)blockIdx.x * blockDim.x + threadIdx.x;
    int d = (int)(gid >> 3);
    if (d >= N) return;
    int q = (int)(gid & 7);
    int k0 = rowptr[d], k1 = rowptr[d + 1];

    float acc[HID];
    #pragma unroll
    for (int i = 0; i < HID; ++i) acc[i] = 0.f;

    for (int k = k0 + q; k < k1; k += 8) {
        int2 v = e2[k];
        unsigned t = ((unsigned)v.x) >> 17;
        int c = 0;
        for (int j = k0; j < k1; ++j)
            c += ((((unsigned)e2[j].x) >> 17) == t);
        float inv = 1.0f / (float)c;
        sinv[k] = inv;
        const vh8* m8 = reinterpret_cast<const vh8*>(msg + (long)v.y * HID);
        vh8 m0 = __builtin_nontemporal_load(m8);
        vh8 m1 = __builtin_nontemporal_load(m8 + 1);
        #pragma unroll
        for (int i = 0; i < 8; ++i) {
            acc[i]     += inv * (float)m0[i];
            acc[i + 8] += inv * (float)m1[i];
        }
    }

    #pragma unroll
    for (int i = 0; i < HID; ++i) {
        acc[i] += __shfl_xor(acc[i], 1);
        acc[i] += __shfl_xor(acc[i], 2);
        acc[i] += __shfl_xor(acc[i], 4);
    }

    if (q == 0) {
        vh8 o0, o1;
        #pragma unroll
        for (int i = 0; i < 8; ++i) {
            o0[i] = (_Float16)(acc[i]     + root1[(size_t)d * HID + i]     + bias1[i]);
            o1[i] = (_Float16)(acc[i + 8] + root1[(size_t)d * HID + i + 8] + bias1[i + 8]);
        }
        vh8* h8 = reinterpret_cast<vh8*>(h + (size_t)d * HID);
        h8[0] = o0;
        h8[1] = o1;
    }
}

// ---------------- layer 2: 8 threads per dst node (k-split), fp16 h, [t][hc] w2 LDS ----------------
__global__ void layer2_kernel(const int2* __restrict__ e2,
                              const int* __restrict__ rowptr,
                              const float* __restrict__ sinv,
                              const float* __restrict__ w2,
                              const _Float16* __restrict__ h,
                              const float* __restrict__ root2,
                              const float* __restrict__ bias2,
                              float* __restrict__ out, int N) {
    __shared__ __align__(16) float w2s[NREL * W2P];    // [t][hc], 26.4 KB
    for (int i = threadIdx.x; i < NREL * HID * NCLS; i += blockDim.x) {
        int t = i / (HID * NCLS);
        int hc = i % (HID * NCLS);
        w2s[t * W2P + hc] = w2[i];
    }
    __syncthreads();

    long gid = (long)blockIdx.x * blockDim.x + threadIdx.x;
    int d = (int)(gid >> 3);
    if (d >= N) return;
    int q = (int)(gid & 7);
    int k0 = rowptr[d], k1 = rowptr[d + 1];

    vf4 accLo = {0.f,0.f,0.f,0.f}, accHi = {0.f,0.f,0.f,0.f};

    for (int k = k0 + q; k < k1; k += 8) {
        int2 v = e2[k];
        int s = v.x & 0x1FFFF;
        int t = ((unsigned)v.x) >> 17;
        float inv = sinv[k];
        const vh8* h8 = reinterpret_cast<const vh8*>(h + (size_t)s * HID);
        vh8 m0 = h8[0];
        vh8 m1 = h8[1];
        float hv[HID];
        #pragma unroll
        for (int i = 0; i < 8; ++i) { hv[i] = (float)m0[i]; hv[i + 8] = (float)m1[i]; }
        const vf4* wp = reinterpret_cast<const vf4*>(w2s + t * W2P);
        vf4 tLo = {0.f,0.f,0.f,0.f}, tHi = {0.f,0.f,0.f,0.f};
        #pragma unroll
        for (int i = 0; i < HID; ++i) {
            tLo += hv[i] * wp[2 * i];
            tHi += hv[i] * wp[2 * i + 1];
        }
        accLo += inv * tLo;
        accHi += inv * tHi;
    }

    float acc[NCLS] = {accLo.x, accLo.y, accLo.z, accLo.w,
                       accHi.x, accHi.y, accHi.z, accHi.w};
    #pragma unroll
    for (int c = 0; c < NCLS; ++c) {
        acc[c] += __shfl_xor(acc[c], 1);
        acc[c] += __shfl_xor(acc[c], 2);
        acc[c] += __shfl_xor(acc[c], 4);
    }

    if (q == 0) {
        const vh8* h8 = reinterpret_cast<const vh8*>(h + (size_t)d * HID);
        vh8 m0 = h8[0];
        vh8 m1 = h8[1];
        float hv[HID];
        #pragma unroll
        for (int i = 0; i < 8; ++i) { hv[i] = (float)m0[i]; hv[i + 8] = (float)m1[i]; }
        #pragma unroll
        for (int i = 0; i < HID; ++i) {
            #pragma unroll
            for (int c = 0; c < NCLS; ++c)
                acc[c] += hv[i] * root2[i * NCLS + c];
        }
        #pragma unroll
        for (int c = 0; c < NCLS; ++c) acc[c] += bias2[c];
        float4* o4 = reinterpret_cast<float4*>(out + (size_t)d * NCLS);
        o4[0] = make_float4(acc[0], acc[1], acc[2], acc[3]);
        o4[1] = make_float4(acc[4], acc[5], acc[6], acc[7]);
    }
}

// ---------------- launch ----------------

extern "C" void kernel_launch(void* const* d_in, const int* in_sizes, int n_in,
                              void* d_out, int out_size, void* d_ws, size_t ws_size,
                              hipStream_t stream) {
    const int*   edge_index = (const int*)  d_in[0];
    const int*   edge_type  = (const int*)  d_in[1];
    const float* basis1     = (const float*)d_in[2];
    const float* comp1      = (const float*)d_in[3];
    const float* root1      = (const float*)d_in[4];
    const float* bias1      = (const float*)d_in[5];
    const float* basis2     = (const float*)d_in[6];
    const float* comp2      = (const float*)d_in[7];
    const float* root2      = (const float*)d_in[8];
    const float* bias2      = (const float*)d_in[9];
    float* out = (float*)d_out;

    const int E = in_sizes[1];
    const int N = in_sizes[4] / HID;
    const int nbuk = (N + BWID - 1) >> SHIFT;
    const int* src = edge_index;
    const int* dst = edge_index + E;

    char* base = (char*)d_ws;
    size_t off = 0;
    auto alloc = [&](size_t bytes, size_t align) -> char* {
        off = (off + align - 1) & ~(align - 1);
        char* p = base + off;
        off += bytes;
        return p;
    };
    // contiguous zero region: hs | hd
    int*  hs       = (int*)  alloc((size_t)NBUKMAX * 4, 4);
    int*  hd       = (int*)  alloc((size_t)NBUKMAX * 4, 4);
    int*  gcs      = (int*)  alloc((size_t)NBUKMAX * 4, 4);
    int*  gcd      = (int*)  alloc((size_t)NBUKMAX * 4, 4);
    int*  bases_s  = (int*)  alloc((size_t)(NBUKMAX + 1) * 4, 4);
    int*  based    = (int*)  alloc((size_t)(NBUKMAX + 1) * 4, 4);
    int*  rowptr   = (int*)  alloc((size_t)(N + 1) * 4, 4);
    int*  rowptr_s = (int*)  alloc((size_t)(N + 1) * 4, 4);
    float* w2      = (float*)alloc((size_t)NREL * HID * NCLS * 4, 16);
    _Float16* h    = (_Float16*)alloc((size_t)N * HID * 2, 16);
    float* sinv    = (float*)alloc((size_t)E * 4, 4);
    int*  Ax0      = (int*)  alloc((size_t)E * 4, 4);
    int*  Ad0      = (int*)  alloc((size_t)E * 4, 4);
    int*  Ax       = (int*)  alloc((size_t)E * 4, 16);
    int*  Ad       = (int*)  alloc((size_t)E * 4, 4);
    int2* B        = (int2*) alloc((size_t)E * 8, 8);
    int2* e2       = (int2*) alloc((size_t)E * 8, 8);
    _Float16* msg  = (_Float16*)alloc((size_t)E * HID * 2, 16);

    hipMemsetAsync(hs, 0, (size_t)NBUKMAX * 2 * 4, stream);

    {   int M = NREL * HID * NCLS;
        compute_w2_kernel<<<(M + 255) / 256, 256, 0, stream>>>(comp2, basis2, w2);
    }
    ghist_kernel<<<2048, 256, 0, stream>>>(src, dst, hs, hd, E, nbuk);
    scanbuk_kernel<<<1, 256, 0, stream>>>(hs, hd, gcs, bases_s, based, gcd, nbuk, E);

    int nblk = (E + TILE - 1) / TILE;
    pass1_kernel<<<nblk, 256, 0, stream>>>(src, dst, edge_type, gcs, Ax0, Ad0, E);
    pass1b_kernel<<<nbuk, 256, 0, stream>>>(Ax0, Ad0, bases_s, Ax, Ad, rowptr_s, N, E);
    pass2_kernel<<<nblk, 256, 0, stream>>>(Ax, Ad, gcd, B, E);
    pass3_kernel<<<nbuk, 256, 0, stream>>>(B, based, e2, rowptr, N, E);

    {   int blocks = (int)((N + 15) / 16);
        layer1A_node_kernel<<<blocks, 256, 0, stream>>>(
            Ax, rowptr_s, comp1, basis1, msg, N);
    }
    {   long total = (long)N * 8;
        layer1B_kernel<<<(int)((total + 255) / 256), 256, 0, stream>>>(
            e2, rowptr, msg, root1, bias1, h, sinv, N);
    }
    {   long total = (long)N * 8;
        layer2_kernel<<<(int)((total + 255) / 256), 256, 0, stream>>>(
            e2, rowptr, sinv, w2, h, root2, bias2, out, N);
    }
}

// Round 21
// 358.466 us; speedup vs baseline: 1.1350x; 1.0091x over previous
//
#include <hip/hip_runtime.h>

#define NREL   50
#define NBASE  30
#define HID    16
#define NCLS   8

#define SHIFT   9
#define BWID    (1 << SHIFT)       // 512 nodes per bucket
#define NBUKMAX 512                // supports N <= 262144
#define TILE    4096               // edges per scatter block
#define EPB     16                 // edges per thread (256 threads)
#define W2P     132                // padded w2 row (floats), 528B 16B-aligned
#define C1P     36                 // padded comp1 row (floats; 144B rotates banks)

typedef float    vf4 __attribute__((ext_vector_type(4)));
typedef _Float16 vh8 __attribute__((ext_vector_type(8)));

// ---------------- setup ----------------

__global__ void compute_w2_kernel(const float* __restrict__ comp2,
                                  const float* __restrict__ basis2,
                                  float* __restrict__ w2) {
    int i = blockIdx.x * blockDim.x + threadIdx.x;
    if (i >= NREL * HID * NCLS) return;
    int r  = i / (HID * NCLS);
    int hc = i % (HID * NCLS);
    float acc = 0.f;
    #pragma unroll
    for (int b = 0; b < NBASE; ++b)
        acc += comp2[r * NBASE + b] * basis2[b * HID * NCLS + hc];
    w2[i] = acc;
}

// ---------------- bucket histograms (LDS-privatized) ----------------

__global__ void ghist_kernel(const int* __restrict__ src,
                             const int* __restrict__ dst,
                             int* __restrict__ hs, int* __restrict__ hd,
                             int E, int nbuk) {
    __shared__ int lhs[NBUKMAX], lhd[NBUKMAX];
    for (int j = threadIdx.x; j < nbuk; j += blockDim.x) { lhs[j] = 0; lhd[j] = 0; }
    __syncthreads();
    for (long e = (long)blockIdx.x * blockDim.x + threadIdx.x; e < E;
         e += (long)gridDim.x * blockDim.x) {
        atomicAdd(&lhs[src[e] >> SHIFT], 1);
        atomicAdd(&lhd[dst[e] >> SHIFT], 1);
    }
    __syncthreads();
    for (int j = threadIdx.x; j < nbuk; j += blockDim.x) {
        if (lhs[j]) atomicAdd(&hs[j], lhs[j]);
        if (lhd[j]) atomicAdd(&hd[j], lhd[j]);
    }
}

// exclusive scans of both histograms; keeps pristine bases for pass1b/pass3
__global__ void scanbuk_kernel(const int* __restrict__ hs, const int* __restrict__ hd,
                               int* __restrict__ gcs, int* __restrict__ bases_s,
                               int* __restrict__ based, int* __restrict__ gcd,
                               int nbuk, int E) {
    __shared__ int a[NBUKMAX], b[NBUKMAX];
    int tid = threadIdx.x;
    for (int j = tid; j < nbuk; j += blockDim.x) { a[j] = hs[j]; b[j] = hd[j]; }
    __syncthreads();
    if (tid == 0) {
        int run = 0;
        for (int i = 0; i < nbuk; ++i) { int v = a[i]; a[i] = run; run += v; }
        run = 0;
        for (int i = 0; i < nbuk; ++i) { int v = b[i]; b[i] = run; run += v; }
    }
    __syncthreads();
    for (int j = tid; j < nbuk; j += blockDim.x) {
        gcs[j] = a[j]; bases_s[j] = a[j];
        based[j] = b[j]; gcd[j] = b[j];
    }
    if (tid == 0) { bases_s[nbuk] = E; based[nbuk] = E; }
}

// ---------------- pass 1: coarse bucket-sort by src>>SHIFT ----------------
__global__ void pass1_kernel(const int* __restrict__ src,
                             const int* __restrict__ dst,
                             const int* __restrict__ et,
                             int* __restrict__ gcur,
                             int* __restrict__ Ax0, int* __restrict__ Ad0, int E) {
    __shared__ int lhist[NBUKMAX], lbase[NBUKMAX], lcur[NBUKMAX];
    int tid = threadIdx.x;
    for (int j = tid; j < NBUKMAX; j += 256) { lhist[j] = 0; lcur[j] = 0; }
    __syncthreads();
    int px[EPB], pd[EPB]; int bk[EPB];
    long e0 = (long)blockIdx.x * TILE;
    #pragma unroll
    for (int j = 0; j < EPB; ++j) {
        long e = e0 + j * 256 + tid;
        if (e < E) {
            int s = src[e], d = dst[e], t = et[e];
            px[j] = s | (t << 17);
            pd[j] = d;
            bk[j] = s >> SHIFT;
            atomicAdd(&lhist[bk[j]], 1);
        } else bk[j] = -1;
    }
    __syncthreads();
    for (int j = tid; j < NBUKMAX; j += 256)
        if (lhist[j] > 0) lbase[j] = atomicAdd(&gcur[j], lhist[j]);
    __syncthreads();
    #pragma unroll
    for (int j = 0; j < EPB; ++j) {
        if (bk[j] >= 0) {
            int r = atomicAdd(&lcur[bk[j]], 1);
            int pos = lbase[bk[j]] + r;
            Ax0[pos] = px[j];
            Ad0[pos] = pd[j];
        }
    }
}

// ---------------- pass 1b: exact src grouping within each bucket ----------------
__global__ void pass1b_kernel(const int* __restrict__ Ax0,
                              const int* __restrict__ Ad0,
                              const int* __restrict__ bases_s,
                              int* __restrict__ Ax, int* __restrict__ Ad,
                              int* __restrict__ rowptr_s, int N, int E) {
    __shared__ int lh[BWID], sA[BWID], sB[BWID];
    int blk = blockIdx.x, tid = threadIdx.x;
    int k0 = bases_s[blk], k1 = bases_s[blk + 1], cnt = k1 - k0;
    for (int j = tid; j < BWID; j += 256) lh[j] = 0;
    __syncthreads();
    for (int i = tid; i < cnt; i += 256) {
        int slow = Ax0[k0 + i] & (BWID - 1);
        atomicAdd(&lh[slow], 1);
    }
    __syncthreads();
    for (int j = tid; j < BWID; j += 256) sA[j] = lh[j];
    __syncthreads();
    int* cur = sA; int* oth = sB;
    for (int off = 1; off < BWID; off <<= 1) {
        for (int j = tid; j < BWID; j += 256)
            oth[j] = cur[j] + (j >= off ? cur[j - off] : 0);
        __syncthreads();
        int* t_ = cur; cur = oth; oth = t_;
    }
    for (int j = tid; j < BWID; j += 256) {
        int excl = cur[j] - lh[j];
        oth[j] = excl;
        int s = blk * BWID + j;
        if (s < N) rowptr_s[s] = k0 + excl;
    }
    __syncthreads();
    for (int i = tid; i < cnt; i += 256) {
        int x = Ax0[k0 + i], d = Ad0[k0 + i];
        int slow = x & (BWID - 1);
        int pos = atomicAdd(&oth[slow], 1);
        Ax[k0 + pos] = x;
        Ad[k0 + pos] = d;
    }
    if (blk == 0 && tid == 0) rowptr_s[N] = E;
}

// ---------------- pass 2: bucket-sort by dst>>SHIFT ----------------
// B[pos] = {s|t<<17, psi | dlow<<21}, psi = index into Ax (= msg row).
__global__ void pass2_kernel(const int* __restrict__ Ax,
                             const int* __restrict__ Ad,
                             int* __restrict__ gcur, int2* __restrict__ B, int E) {
    __shared__ int lhist[NBUKMAX], lbase[NBUKMAX], lcur[NBUKMAX];
    int tid = threadIdx.x;
    for (int j = tid; j < NBUKMAX; j += 256) { lhist[j] = 0; lcur[j] = 0; }
    __syncthreads();
    int2 p[EPB]; int bk[EPB];
    long e0 = (long)blockIdx.x * TILE;
    #pragma unroll
    for (int j = 0; j < EPB; ++j) {
        long e = e0 + j * 256 + tid;
        if (e < E) {
            int x = Ax[e];
            int d = Ad[e];
            p[j] = make_int2(x, (int)e | ((d & (BWID - 1)) << 21));
            bk[j] = d >> SHIFT;
            atomicAdd(&lhist[bk[j]], 1);
        } else bk[j] = -1;
    }
    __syncthreads();
    for (int j = tid; j < NBUKMAX; j += 256)
        if (lhist[j] > 0) lbase[j] = atomicAdd(&gcur[j], lhist[j]);
    __syncthreads();
    #pragma unroll
    for (int j = 0; j < EPB; ++j) {
        if (bk[j] >= 0) {
            int r = atomicAdd(&lcur[bk[j]], 1);
            B[lbase[bk[j]] + r] = p[j];
        }
    }
}

// ---------------- pass 3: exact dst grouping within each bucket ----------------
__global__ void pass3_kernel(const int2* __restrict__ B,
                             const int* __restrict__ based,
                             int2* __restrict__ e2, int* __restrict__ rowptr,
                             int N, int E) {
    __shared__ int lh[BWID], sA[BWID], sB[BWID];
    int blk = blockIdx.x, tid = threadIdx.x;
    int k0 = based[blk], k1 = based[blk + 1], cnt = k1 - k0;
    for (int j = tid; j < BWID; j += 256) lh[j] = 0;
    __syncthreads();
    for (int i = tid; i < cnt; i += 256) {
        int dlow = ((unsigned)B[k0 + i].y) >> 21;
        atomicAdd(&lh[dlow], 1);
    }
    __syncthreads();
    for (int j = tid; j < BWID; j += 256) sA[j] = lh[j];
    __syncthreads();
    int* cur = sA; int* oth = sB;
    for (int off = 1; off < BWID; off <<= 1) {
        for (int j = tid; j < BWID; j += 256)
            oth[j] = cur[j] + (j >= off ? cur[j - off] : 0);
        __syncthreads();
        int* t_ = cur; cur = oth; oth = t_;
    }
    for (int j = tid; j < BWID; j += 256) {
        int excl = cur[j] - lh[j];
        oth[j] = excl;
        int d = blk * BWID + j;
        if (d < N) rowptr[d] = k0 + excl;
    }
    __syncthreads();
    for (int i = tid; i < cnt; i += 256) {
        int2 b = B[k0 + i];
        int dlow = ((unsigned)b.y) >> 21;
        int pos = atomicAdd(&oth[dlow], 1);
        e2[k0 + pos] = make_int2(b.x, b.y & 0x1FFFFF);
    }
    if (blk == 0 && tid == 0) rowptr[N] = E;
}

// ---------------- layer 1 phase A: node-centric, pipelined 4-edge ILP, fp16 msg ----------------
__global__ void layer1A_node_kernel(const int* __restrict__ Ax,
                                    const int* __restrict__ rowptr_s,
                                    const float* __restrict__ comp1,
                                    const float* __restrict__ basis1,
                                    _Float16* __restrict__ msg, int N) {
    __shared__ float c1s[NREL * C1P];
    for (int i = threadIdx.x; i < NREL * C1P; i += blockDim.x) {
        int t = i / C1P, b = i % C1P;
        c1s[i] = (b < NBASE) ? comp1[t * NBASE + b] : 0.f;
    }
    __syncthreads();
    int gid = threadIdx.x >> 4;
    int l   = threadIdx.x & 15;
    int s = blockIdx.x * 16 + gid;
    if (s >= N) return;
    int k0 = rowptr_s[s], k1 = rowptr_s[s + 1];
    if (k0 == k1) return;

    vf4 b4[8];
    {
        long stride = (long)N * HID;
        const float* bp = basis1 + (long)s * HID + l;
        float breg[32];
        #pragma unroll
        for (int b = 0; b < NBASE; ++b)
            breg[b] = bp[(long)b * stride];
        #pragma unroll
        for (int b = NBASE; b < 32; ++b) breg[b] = 0.f;
        #pragma unroll
        for (int i = 0; i < 8; ++i)
            b4[i] = (vf4){breg[4*i], breg[4*i+1], breg[4*i+2], breg[4*i+3]};
    }

    int k = k0;
    if (k + 4 <= k1) {
        int c0x = Ax[k + 0], c1x = Ax[k + 1], c2x = Ax[k + 2], c3x = Ax[k + 3];
        for (;;) {
            bool more = (k + 8 <= k1);
            int n0, n1, n2, n3;
            if (more) {                       // prefetch next batch's records
                n0 = Ax[k + 4]; n1 = Ax[k + 5]; n2 = Ax[k + 6]; n3 = Ax[k + 7];
            }
            const vf4* c0 = reinterpret_cast<const vf4*>(c1s + (((unsigned)c0x) >> 17) * C1P);
            const vf4* c1 = reinterpret_cast<const vf4*>(c1s + (((unsigned)c1x) >> 17) * C1P);
            const vf4* c2 = reinterpret_cast<const vf4*>(c1s + (((unsigned)c2x) >> 17) * C1P);
            const vf4* c3 = reinterpret_cast<const vf4*>(c1s + (((unsigned)c3x) >> 17) * C1P);
            vf4 a0 = {0.f,0.f,0.f,0.f}, a1 = a0, a2 = a0, a3 = a0;
            #pragma unroll
            for (int i = 0; i < 8; ++i) {
                a0 += c0[i] * b4[i];
                a1 += c1[i] * b4[i];
                a2 += c2[i] * b4[i];
                a3 += c3[i] * b4[i];
            }
            float r0 = (a0.x + a0.y) + (a0.z + a0.w);
            float r1 = (a1.x + a1.y) + (a1.z + a1.w);
            float r2 = (a2.x + a2.y) + (a2.z + a2.w);
            float r3 = (a3.x + a3.y) + (a3.z + a3.w);
            __builtin_nontemporal_store((_Float16)r0, &msg[(long)(k + 0) * HID + l]);
            __builtin_nontemporal_store((_Float16)r1, &msg[(long)(k + 1) * HID + l]);
            __builtin_nontemporal_store((_Float16)r2, &msg[(long)(k + 2) * HID + l]);
            __builtin_nontemporal_store((_Float16)r3, &msg[(long)(k + 3) * HID + l]);
            k += 4;
            if (!more) break;
            c0x = n0; c1x = n1; c2x = n2; c3x = n3;
        }
    }
    for (; k < k1; ++k) {
        int t = ((unsigned)Ax[k]) >> 17;
        const vf4* cr4 = reinterpret_cast<const vf4*>(c1s + t * C1P);
        vf4 acc4 = {0.f, 0.f, 0.f, 0.f};
        #pragma unroll
        for (int i = 0; i < 8; ++i)
            acc4 += cr4[i] * b4[i];
        float acc = (acc4.x + acc4.y) + (acc4.z + acc4.w);
        __builtin_nontemporal_store((_Float16)acc, &msg[(long)k * HID + l]);
    }
}

// ---------------- layer 1 phase B: 8 threads per dst node, fp16 msg gather, fp16 h out ----------------
__global__ void layer1B_kernel(const int2* __restrict__ e2,
                               const int* __restrict__ rowptr,
                               const _Float16* __restrict__ msg,
                               const float* __restrict__ root1,
                               const float* __restrict__ bias1,
                               _Float16* __restrict__ h, float* __restrict__ sinv, int N) {
    long gid = (long)blockIdx.x * blockDim.x + threadIdx.x;
    int d = (int)(gid >> 3);
    if (d >= N) return;
    int q = (int)(gid & 7);
    int k0 = rowptr[d], k1 = rowptr[d + 1];

    float acc[HID];
    #pragma unroll
    for (int i = 0; i < HID; ++i) acc[i] = 0.f;

    for (int k = k0 + q; k < k1; k += 8) {
        int2 v = e2[k];
        unsigned t = ((unsigned)v.x) >> 17;
        int c = 0;
        for (int j = k0; j < k1; ++j)
            c += ((((unsigned)e2[j].x) >> 17) == t);
        float inv = 1.0f / (float)c;
        sinv[k] = inv;
        const vh8* m8 = reinterpret_cast<const vh8*>(msg + (long)v.y * HID);
        vh8 m0 = __builtin_nontemporal_load(m8);
        vh8 m1 = __builtin_nontemporal_load(m8 + 1);
        #pragma unroll
        for (int i = 0; i < 8; ++i) {
            acc[i]     += inv * (float)m0[i];
            acc[i + 8] += inv * (float)m1[i];
        }
    }

    #pragma unroll
    for (int i = 0; i < HID; ++i) {
        acc[i] += __shfl_xor(acc[i], 1);
        acc[i] += __shfl_xor(acc[i], 2);
        acc[i] += __shfl_xor(acc[i], 4);
    }

    if (q == 0) {
        vh8 o0, o1;
        #pragma unroll
        for (int i = 0; i < 8; ++i) {
            o0[i] = (_Float16)(acc[i]     + root1[(size_t)d * HID + i]     + bias1[i]);
            o1[i] = (_Float16)(acc[i + 8] + root1[(size_t)d * HID + i + 8] + bias1[i + 8]);
        }
        vh8* h8 = reinterpret_cast<vh8*>(h + (size_t)d * HID);
        h8[0] = o0;
        h8[1] = o1;
    }
}

// ---------------- layer 2: 8 threads per dst node (k-split), fp16 h, [t][hc] w2 LDS ----------------
__global__ void layer2_kernel(const int2* __restrict__ e2,
                              const int* __restrict__ rowptr,
                              const float* __restrict__ sinv,
                              const float* __restrict__ w2,
                              const _Float16* __restrict__ h,
                              const float* __restrict__ root2,
                              const float* __restrict__ bias2,
                              float* __restrict__ out, int N) {
    __shared__ __align__(16) float w2s[NREL * W2P];    // [t][hc], 26.4 KB
    for (int i = threadIdx.x; i < NREL * HID * NCLS; i += blockDim.x) {
        int t = i / (HID * NCLS);
        int hc = i % (HID * NCLS);
        w2s[t * W2P + hc] = w2[i];
    }
    __syncthreads();

    long gid = (long)blockIdx.x * blockDim.x + threadIdx.x;
    int d = (int)(gid >> 3);
    if (d >= N) return;
    int q = (int)(gid & 7);
    int k0 = rowptr[d], k1 = rowptr[d + 1];

    vf4 accLo = {0.f,0.f,0.f,0.f}, accHi = {0.f,0.f,0.f,0.f};

    for (int k = k0 + q; k < k1; k += 8) {
        int2 v = e2[k];
        int s = v.x & 0x1FFFF;
        int t = ((unsigned)v.x) >> 17;
        float inv = sinv[k];
        const vh8* h8 = reinterpret_cast<const vh8*>(h + (size_t)s * HID);
        vh8 m0 = h8[0];
        vh8 m1 = h8[1];
        float hv[HID];
        #pragma unroll
        for (int i = 0; i < 8; ++i) { hv[i] = (float)m0[i]; hv[i + 8] = (float)m1[i]; }
        const vf4* wp = reinterpret_cast<const vf4*>(w2s + t * W2P);
        vf4 tLo = {0.f,0.f,0.f,0.f}, tHi = {0.f,0.f,0.f,0.f};
        #pragma unroll
        for (int i = 0; i < HID; ++i) {
            tLo += hv[i] * wp[2 * i];
            tHi += hv[i] * wp[2 * i + 1];
        }
        accLo += inv * tLo;
        accHi += inv * tHi;
    }

    float acc[NCLS] = {accLo.x, accLo.y, accLo.z, accLo.w,
                       accHi.x, accHi.y, accHi.z, accHi.w};
    #pragma unroll
    for (int c = 0; c < NCLS; ++c) {
        acc[c] += __shfl_xor(acc[c], 1);
        acc[c] += __shfl_xor(acc[c], 2);
        acc[c] += __shfl_xor(acc[c], 4);
    }

    if (q == 0) {
        const vh8* h8 = reinterpret_cast<const vh8*>(h + (size_t)d * HID);
        vh8 m0 = h8[0];
        vh8 m1 = h8[1];
        float hv[HID];
        #pragma unroll
        for (int i = 0; i < 8; ++i) { hv[i] = (float)m0[i]; hv[i + 8] = (float)m1[i]; }
        #pragma unroll
        for (int i = 0; i < HID; ++i) {
            #pragma unroll
            for (int c = 0; c < NCLS; ++c)
                acc[c] += hv[i] * root2[i * NCLS + c];
        }
        #pragma unroll
        for (int c = 0; c < NCLS; ++c) acc[c] += bias2[c];
        float4* o4 = reinterpret_cast<float4*>(out + (size_t)d * NCLS);
        o4[0] = make_float4(acc[0], acc[1], acc[2], acc[3]);
        o4[1] = make_float4(acc[4], acc[5], acc[6], acc[7]);
    }
}

// ---------------- launch ----------------

extern "C" void kernel_launch(void* const* d_in, const int* in_sizes, int n_in,
                              void* d_out, int out_size, void* d_ws, size_t ws_size,
                              hipStream_t stream) {
    const int*   edge_index = (const int*)  d_in[0];
    const int*   edge_type  = (const int*)  d_in[1];
    const float* basis1     = (const float*)d_in[2];
    const float* comp1      = (const float*)d_in[3];
    const float* root1      = (const float*)d_in[4];
    const float* bias1      = (const float*)d_in[5];
    const float* basis2     = (const float*)d_in[6];
    const float* comp2      = (const float*)d_in[7];
    const float* root2      = (const float*)d_in[8];
    const float* bias2      = (const float*)d_in[9];
    float* out = (float*)d_out;

    const int E = in_sizes[1];
    const int N = in_sizes[4] / HID;
    const int nbuk = (N + BWID - 1) >> SHIFT;
    const int* src = edge_index;
    const int* dst = edge_index + E;

    char* base = (char*)d_ws;
    size_t off = 0;
    auto alloc = [&](size_t bytes, size_t align) -> char* {
        off = (off + align - 1) & ~(align - 1);
        char* p = base + off;
        off += bytes;
        return p;
    };
    // contiguous zero region: hs | hd
    int*  hs       = (int*)  alloc((size_t)NBUKMAX * 4, 4);
    int*  hd       = (int*)  alloc((size_t)NBUKMAX * 4, 4);
    int*  gcs      = (int*)  alloc((size_t)NBUKMAX * 4, 4);
    int*  gcd      = (int*)  alloc((size_t)NBUKMAX * 4, 4);
    int*  bases_s  = (int*)  alloc((size_t)(NBUKMAX + 1) * 4, 4);
    int*  based    = (int*)  alloc((size_t)(NBUKMAX + 1) * 4, 4);
    int*  rowptr   = (int*)  alloc((size_t)(N + 1) * 4, 4);
    int*  rowptr_s = (int*)  alloc((size_t)(N + 1) * 4, 4);
    float* w2      = (float*)alloc((size_t)NREL * HID * NCLS * 4, 16);
    _Float16* h    = (_Float16*)alloc((size_t)N * HID * 2, 16);
    float* sinv    = (float*)alloc((size_t)E * 4, 4);
    int*  Ax0      = (int*)  alloc((size_t)E * 4, 4);
    int*  Ad0      = (int*)  alloc((size_t)E * 4, 4);
    int*  Ax       = (int*)  alloc((size_t)E * 4, 16);
    int*  Ad       = (int*)  alloc((size_t)E * 4, 4);
    int2* B        = (int2*) alloc((size_t)E * 8, 8);
    int2* e2       = (int2*) alloc((size_t)E * 8, 8);
    _Float16* msg  = (_Float16*)alloc((size_t)E * HID * 2, 16);

    hipMemsetAsync(hs, 0, (size_t)NBUKMAX * 2 * 4, stream);

    {   int M = NREL * HID * NCLS;
        compute_w2_kernel<<<(M + 255) / 256, 256, 0, stream>>>(comp2, basis2, w2);
    }
    ghist_kernel<<<2048, 256, 0, stream>>>(src, dst, hs, hd, E, nbuk);
    scanbuk_kernel<<<1, 256, 0, stream>>>(hs, hd, gcs, bases_s, based, gcd, nbuk, E);

    int nblk = (E + TILE - 1) / TILE;
    pass1_kernel<<<nblk, 256, 0, stream>>>(src, dst, edge_type, gcs, Ax0, Ad0, E);
    pass1b_kernel<<<nbuk, 256, 0, stream>>>(Ax0, Ad0, bases_s, Ax, Ad, rowptr_s, N, E);
    pass2_kernel<<<nblk, 256, 0, stream>>>(Ax, Ad, gcd, B, E);
    pass3_kernel<<<nbuk, 256, 0, stream>>>(B, based, e2, rowptr, N, E);

    {   int blocks = (int)((N + 15) / 16);
        layer1A_node_kernel<<<blocks, 256, 0, stream>>>(
            Ax, rowptr_s, comp1, basis1, msg, N);
    }
    {   long total = (long)N * 8;
        layer1B_kernel<<<(int)((total + 255) / 256), 256, 0, stream>>>(
            e2, rowptr, msg, root1, bias1, h, sinv, N);
    }
    {   long total = (long)N * 8;
        layer2_kernel<<<(int)((total + 255) / 256), 256, 0, stream>>>(
            e2, rowptr, sinv, w2, h, root2, bias2, out, N);
    }
}

// Round 22
// 352.318 us; speedup vs baseline: 1.1549x; 1.0174x over previous
//
#include <hip/hip_runtime.h>

#define NREL   50
#define NBASE  30
#define HID    16
#define NCLS   8

#define SHIFT   8
#define BWID    (1 << SHIFT)       // 256 nodes per bucket
#define NBUKMAX 512                // supports N <= 131072 at SHIFT=8
#define TILE    4096               // edges per scatter block
#define EPB     16                 // edges per thread (256 threads)
#define W2P     132                // padded w2 row (floats), 528B 16B-aligned
#define C1P     36                 // padded comp1 row (floats; 144B rotates banks)

typedef float    vf4 __attribute__((ext_vector_type(4)));
typedef _Float16 vh8 __attribute__((ext_vector_type(8)));

// ---------------- setup ----------------

__global__ void compute_w2_kernel(const float* __restrict__ comp2,
                                  const float* __restrict__ basis2,
                                  float* __restrict__ w2) {
    int i = blockIdx.x * blockDim.x + threadIdx.x;
    if (i >= NREL * HID * NCLS) return;
    int r  = i / (HID * NCLS);
    int hc = i % (HID * NCLS);
    float acc = 0.f;
    #pragma unroll
    for (int b = 0; b < NBASE; ++b)
        acc += comp2[r * NBASE + b] * basis2[b * HID * NCLS + hc];
    w2[i] = acc;
}

// ---------------- bucket histograms (LDS-privatized) ----------------

__global__ void ghist_kernel(const int* __restrict__ src,
                             const int* __restrict__ dst,
                             int* __restrict__ hs, int* __restrict__ hd,
                             int E, int nbuk) {
    __shared__ int lhs[NBUKMAX], lhd[NBUKMAX];
    for (int j = threadIdx.x; j < nbuk; j += blockDim.x) { lhs[j] = 0; lhd[j] = 0; }
    __syncthreads();
    for (long e = (long)blockIdx.x * blockDim.x + threadIdx.x; e < E;
         e += (long)gridDim.x * blockDim.x) {
        atomicAdd(&lhs[src[e] >> SHIFT], 1);
        atomicAdd(&lhd[dst[e] >> SHIFT], 1);
    }
    __syncthreads();
    for (int j = threadIdx.x; j < nbuk; j += blockDim.x) {
        if (lhs[j]) atomicAdd(&hs[j], lhs[j]);
        if (lhd[j]) atomicAdd(&hd[j], lhd[j]);
    }
}

// exclusive scans of both histograms; keeps pristine bases for pass1b/pass3
__global__ void scanbuk_kernel(const int* __restrict__ hs, const int* __restrict__ hd,
                               int* __restrict__ gcs, int* __restrict__ bases_s,
                               int* __restrict__ based, int* __restrict__ gcd,
                               int nbuk, int E) {
    __shared__ int a[NBUKMAX], b[NBUKMAX];
    int tid = threadIdx.x;
    for (int j = tid; j < nbuk; j += blockDim.x) { a[j] = hs[j]; b[j] = hd[j]; }
    __syncthreads();
    if (tid == 0) {
        int run = 0;
        for (int i = 0; i < nbuk; ++i) { int v = a[i]; a[i] = run; run += v; }
        run = 0;
        for (int i = 0; i < nbuk; ++i) { int v = b[i]; b[i] = run; run += v; }
    }
    __syncthreads();
    for (int j = tid; j < nbuk; j += blockDim.x) {
        gcs[j] = a[j]; bases_s[j] = a[j];
        based[j] = b[j]; gcd[j] = b[j];
    }
    if (tid == 0) { bases_s[nbuk] = E; based[nbuk] = E; }
}

// ---------------- pass 1: coarse bucket-sort by src>>SHIFT ----------------
__global__ void pass1_kernel(const int* __restrict__ src,
                             const int* __restrict__ dst,
                             const int* __restrict__ et,
                             int* __restrict__ gcur,
                             int* __restrict__ Ax0, int* __restrict__ Ad0, int E) {
    __shared__ int lhist[NBUKMAX], lbase[NBUKMAX], lcur[NBUKMAX];
    int tid = threadIdx.x;
    for (int j = tid; j < NBUKMAX; j += 256) { lhist[j] = 0; lcur[j] = 0; }
    __syncthreads();
    int px[EPB], pd[EPB]; int bk[EPB];
    long e0 = (long)blockIdx.x * TILE;
    #pragma unroll
    for (int j = 0; j < EPB; ++j) {
        long e = e0 + j * 256 + tid;
        if (e < E) {
            int s = src[e], d = dst[e], t = et[e];
            px[j] = s | (t << 17);
            pd[j] = d;
            bk[j] = s >> SHIFT;
            atomicAdd(&lhist[bk[j]], 1);
        } else bk[j] = -1;
    }
    __syncthreads();
    for (int j = tid; j < NBUKMAX; j += 256)
        if (lhist[j] > 0) lbase[j] = atomicAdd(&gcur[j], lhist[j]);
    __syncthreads();
    #pragma unroll
    for (int j = 0; j < EPB; ++j) {
        if (bk[j] >= 0) {
            int r = atomicAdd(&lcur[bk[j]], 1);
            int pos = lbase[bk[j]] + r;
            Ax0[pos] = px[j];
            Ad0[pos] = pd[j];
        }
    }
}

// ---------------- pass 1b: exact src grouping within each bucket (512 threads) ----------------
__global__ void pass1b_kernel(const int* __restrict__ Ax0,
                              const int* __restrict__ Ad0,
                              const int* __restrict__ bases_s,
                              int* __restrict__ Ax, int* __restrict__ Ad,
                              int* __restrict__ rowptr_s, int N, int E) {
    __shared__ int lh[BWID], sA[BWID], sB[BWID];
    int blk = blockIdx.x, tid = threadIdx.x;
    int nt = blockDim.x;
    int k0 = bases_s[blk], k1 = bases_s[blk + 1], cnt = k1 - k0;
    for (int j = tid; j < BWID; j += nt) lh[j] = 0;
    __syncthreads();
    for (int i = tid; i < cnt; i += nt) {
        int slow = Ax0[k0 + i] & (BWID - 1);
        atomicAdd(&lh[slow], 1);
    }
    __syncthreads();
    for (int j = tid; j < BWID; j += nt) sA[j] = lh[j];
    __syncthreads();
    int* cur = sA; int* oth = sB;
    for (int off = 1; off < BWID; off <<= 1) {
        for (int j = tid; j < BWID; j += nt)
            oth[j] = cur[j] + (j >= off ? cur[j - off] : 0);
        __syncthreads();
        int* t_ = cur; cur = oth; oth = t_;
    }
    for (int j = tid; j < BWID; j += nt) {
        int excl = cur[j] - lh[j];
        oth[j] = excl;
        int s = blk * BWID + j;
        if (s < N) rowptr_s[s] = k0 + excl;
    }
    __syncthreads();
    for (int i = tid; i < cnt; i += nt) {
        int x = Ax0[k0 + i], d = Ad0[k0 + i];
        int slow = x & (BWID - 1);
        int pos = atomicAdd(&oth[slow], 1);
        Ax[k0 + pos] = x;
        Ad[k0 + pos] = d;
    }
    if (blk == 0 && tid == 0) rowptr_s[N] = E;
}

// ---------------- pass 2: bucket-sort by dst>>SHIFT ----------------
// B[pos] = {s|t<<17, psi | dlow<<21}, psi = index into Ax (= msg row).
__global__ void pass2_kernel(const int* __restrict__ Ax,
                             const int* __restrict__ Ad,
                             int* __restrict__ gcur, int2* __restrict__ B, int E) {
    __shared__ int lhist[NBUKMAX], lbase[NBUKMAX], lcur[NBUKMAX];
    int tid = threadIdx.x;
    for (int j = tid; j < NBUKMAX; j += 256) { lhist[j] = 0; lcur[j] = 0; }
    __syncthreads();
    int2 p[EPB]; int bk[EPB];
    long e0 = (long)blockIdx.x * TILE;
    #pragma unroll
    for (int j = 0; j < EPB; ++j) {
        long e = e0 + j * 256 + tid;
        if (e < E) {
            int x = Ax[e];
            int d = Ad[e];
            p[j] = make_int2(x, (int)e | ((d & (BWID - 1)) << 21));
            bk[j] = d >> SHIFT;
            atomicAdd(&lhist[bk[j]], 1);
        } else bk[j] = -1;
    }
    __syncthreads();
    for (int j = tid; j < NBUKMAX; j += 256)
        if (lhist[j] > 0) lbase[j] = atomicAdd(&gcur[j], lhist[j]);
    __syncthreads();
    #pragma unroll
    for (int j = 0; j < EPB; ++j) {
        if (bk[j] >= 0) {
            int r = atomicAdd(&lcur[bk[j]], 1);
            B[lbase[bk[j]] + r] = p[j];
        }
    }
}

// ---------------- pass 3: exact dst grouping within each bucket (512 threads) ----------------
__global__ void pass3_kernel(const int2* __restrict__ B,
                             const int* __restrict__ based,
                             int2* __restrict__ e2, int* __restrict__ rowptr,
                             int N, int E) {
    __shared__ int lh[BWID], sA[BWID], sB[BWID];
    int blk = blockIdx.x, tid = threadIdx.x;
    int nt = blockDim.x;
    int k0 = based[blk], k1 = based[blk + 1], cnt = k1 - k0;
    for (int j = tid; j < BWID; j += nt) lh[j] = 0;
    __syncthreads();
    for (int i = tid; i < cnt; i += nt) {
        int dlow = ((unsigned)B[k0 + i].y) >> 21;
        atomicAdd(&lh[dlow], 1);
    }
    __syncthreads();
    for (int j = tid; j < BWID; j += nt) sA[j] = lh[j];
    __syncthreads();
    int* cur = sA; int* oth = sB;
    for (int off = 1; off < BWID; off <<= 1) {
        for (int j = tid; j < BWID; j += nt)
            oth[j] = cur[j] + (j >= off ? cur[j - off] : 0);
        __syncthreads();
        int* t_ = cur; cur = oth; oth = t_;
    }
    for (int j = tid; j < BWID; j += nt) {
        int excl = cur[j] - lh[j];
        oth[j] = excl;
        int d = blk * BWID + j;
        if (d < N) rowptr[d] = k0 + excl;
    }
    __syncthreads();
    for (int i = tid; i < cnt; i += nt) {
        int2 b = B[k0 + i];
        int dlow = ((unsigned)b.y) >> 21;
        int pos = atomicAdd(&oth[dlow], 1);
        e2[k0 + pos] = make_int2(b.x, b.y & 0x1FFFFF);
    }
    if (blk == 0 && tid == 0) rowptr[N] = E;
}

// ---------------- layer 1 phase A: node-centric, pipelined 4-edge ILP, fp16 msg ----------------
__global__ void layer1A_node_kernel(const int* __restrict__ Ax,
                                    const int* __restrict__ rowptr_s,
                                    const float* __restrict__ comp1,
                                    const float* __restrict__ basis1,
                                    _Float16* __restrict__ msg, int N) {
    __shared__ float c1s[NREL * C1P];
    for (int i = threadIdx.x; i < NREL * C1P; i += blockDim.x) {
        int t = i / C1P, b = i % C1P;
        c1s[i] = (b < NBASE) ? comp1[t * NBASE + b] : 0.f;
    }
    __syncthreads();
    int gid = threadIdx.x >> 4;
    int l   = threadIdx.x & 15;
    int s = blockIdx.x * 16 + gid;
    if (s >= N) return;
    int k0 = rowptr_s[s], k1 = rowptr_s[s + 1];
    if (k0 == k1) return;

    vf4 b4[8];
    {
        long stride = (long)N * HID;
        const float* bp = basis1 + (long)s * HID + l;
        float breg[32];
        #pragma unroll
        for (int b = 0; b < NBASE; ++b)
            breg[b] = bp[(long)b * stride];
        #pragma unroll
        for (int b = NBASE; b < 32; ++b) breg[b] = 0.f;
        #pragma unroll
        for (int i = 0; i < 8; ++i)
            b4[i] = (vf4){breg[4*i], breg[4*i+1], breg[4*i+2], breg[4*i+3]};
    }

    int k = k0;
    if (k + 4 <= k1) {
        int c0x = Ax[k + 0], c1x = Ax[k + 1], c2x = Ax[k + 2], c3x = Ax[k + 3];
        for (;;) {
            bool more = (k + 8 <= k1);
            int n0, n1, n2, n3;
            if (more) {
                n0 = Ax[k + 4]; n1 = Ax[k + 5]; n2 = Ax[k + 6]; n3 = Ax[k + 7];
            }
            const vf4* c0 = reinterpret_cast<const vf4*>(c1s + (((unsigned)c0x) >> 17) * C1P);
            const vf4* c1 = reinterpret_cast<const vf4*>(c1s + (((unsigned)c1x) >> 17) * C1P);
            const vf4* c2 = reinterpret_cast<const vf4*>(c1s + (((unsigned)c2x) >> 17) * C1P);
            const vf4* c3 = reinterpret_cast<const vf4*>(c1s + (((unsigned)c3x) >> 17) * C1P);
            vf4 a0 = {0.f,0.f,0.f,0.f}, a1 = a0, a2 = a0, a3 = a0;
            #pragma unroll
            for (int i = 0; i < 8; ++i) {
                a0 += c0[i] * b4[i];
                a1 += c1[i] * b4[i];
                a2 += c2[i] * b4[i];
                a3 += c3[i] * b4[i];
            }
            float r0 = (a0.x + a0.y) + (a0.z + a0.w);
            float r1 = (a1.x + a1.y) + (a1.z + a1.w);
            float r2 = (a2.x + a2.y) + (a2.z + a2.w);
            float r3 = (a3.x + a3.y) + (a3.z + a3.w);
            __builtin_nontemporal_store((_Float16)r0, &msg[(long)(k + 0) * HID + l]);
            __builtin_nontemporal_store((_Float16)r1, &msg[(long)(k + 1) * HID + l]);
            __builtin_nontemporal_store((_Float16)r2, &msg[(long)(k + 2) * HID + l]);
            __builtin_nontemporal_store((_Float16)r3, &msg[(long)(k + 3) * HID + l]);
            k += 4;
            if (!more) break;
            c0x = n0; c1x = n1; c2x = n2; c3x = n3;
        }
    }
    for (; k < k1; ++k) {
        int t = ((unsigned)Ax[k]) >> 17;
        const vf4* cr4 = reinterpret_cast<const vf4*>(c1s + t * C1P);
        vf4 acc4 = {0.f, 0.f, 0.f, 0.f};
        #pragma unroll
        for (int i = 0; i < 8; ++i)
            acc4 += cr4[i] * b4[i];
        float acc = (acc4.x + acc4.y) + (acc4.z + acc4.w);
        __builtin_nontemporal_store((_Float16)acc, &msg[(long)k * HID + l]);
    }
}

// ---------------- layer 1 phase B: 8 threads per dst node, fp16 msg gather, fp16 h out ----------------
__global__ void layer1B_kernel(const int2* __restrict__ e2,
                               const int* __restrict__ rowptr,
                               const _Float16* __restrict__ msg,
                               const float* __restrict__ root1,
                               const float* __restrict__ bias1,
                               _Float16* __restrict__ h, float* __restrict__ sinv, int N) {
    long gid = (long)blockIdx.x * blockDim.x + threadIdx.x;
    int d = (int)(gid >> 3);
    if (d >= N) return;
    int q = (int)(gid & 7);
    int k0 = rowptr[d], k1 = rowptr[d + 1];

    float acc[HID];
    #pragma unroll
    for (int i = 0; i < HID; ++i) acc[i] = 0.f;

    for (int k = k0 + q; k < k1; k += 8) {
        int2 v = e2[k];
        unsigned t = ((unsigned)v.x) >> 17;
        int c = 0;
        for (int j = k0; j < k1; ++j)
            c += ((((unsigned)e2[j].x) >> 17) == t);
        float inv = 1.0f / (float)c;
        sinv[k] = inv;
        const vh8* m8 = reinterpret_cast<const vh8*>(msg + (long)v.y * HID);
        vh8 m0 = __builtin_nontemporal_load(m8);
        vh8 m1 = __builtin_nontemporal_load(m8 + 1);
        #pragma unroll
        for (int i = 0; i < 8; ++i) {
            acc[i]     += inv * (float)m0[i];
            acc[i + 8] += inv * (float)m1[i];
        }
    }

    #pragma unroll
    for (int i = 0; i < HID; ++i) {
        acc[i] += __shfl_xor(acc[i], 1);
        acc[i] += __shfl_xor(acc[i], 2);
        acc[i] += __shfl_xor(acc[i], 4);
    }

    if (q == 0) {
        vh8 o0, o1;
        #pragma unroll
        for (int i = 0; i < 8; ++i) {
            o0[i] = (_Float16)(acc[i]     + root1[(size_t)d * HID + i]     + bias1[i]);
            o1[i] = (_Float16)(acc[i + 8] + root1[(size_t)d * HID + i + 8] + bias1[i + 8]);
        }
        vh8* h8 = reinterpret_cast<vh8*>(h + (size_t)d * HID);
        h8[0] = o0;
        h8[1] = o1;
    }
}

// ---------------- layer 2: 8 threads per dst node (k-split), fp16 h, [t][hc] w2 LDS ----------------
__global__ void layer2_kernel(const int2* __restrict__ e2,
                              const int* __restrict__ rowptr,
                              const float* __restrict__ sinv,
                              const float* __restrict__ w2,
                              const _Float16* __restrict__ h,
                              const float* __restrict__ root2,
                              const float* __restrict__ bias2,
                              float* __restrict__ out, int N) {
    __shared__ __align__(16) float w2s[NREL * W2P];    // [t][hc], 26.4 KB
    for (int i = threadIdx.x; i < NREL * HID * NCLS; i += blockDim.x) {
        int t = i / (HID * NCLS);
        int hc = i % (HID * NCLS);
        w2s[t * W2P + hc] = w2[i];
    }
    __syncthreads();

    long gid = (long)blockIdx.x * blockDim.x + threadIdx.x;
    int d = (int)(gid >> 3);
    if (d >= N) return;
    int q = (int)(gid & 7);
    int k0 = rowptr[d], k1 = rowptr[d + 1];

    vf4 accLo = {0.f,0.f,0.f,0.f}, accHi = {0.f,0.f,0.f,0.f};

    for (int k = k0 + q; k < k1; k += 8) {
        int2 v = e2[k];
        int s = v.x & 0x1FFFF;
        int t = ((unsigned)v.x) >> 17;
        float inv = sinv[k];
        const vh8* h8 = reinterpret_cast<const vh8*>(h + (size_t)s * HID);
        vh8 m0 = h8[0];
        vh8 m1 = h8[1];
        float hv[HID];
        #pragma unroll
        for (int i = 0; i < 8; ++i) { hv[i] = (float)m0[i]; hv[i + 8] = (float)m1[i]; }
        const vf4* wp = reinterpret_cast<const vf4*>(w2s + t * W2P);
        vf4 tLo = {0.f,0.f,0.f,0.f}, tHi = {0.f,0.f,0.f,0.f};
        #pragma unroll
        for (int i = 0; i < HID; ++i) {
            tLo += hv[i] * wp[2 * i];
            tHi += hv[i] * wp[2 * i + 1];
        }
        accLo += inv * tLo;
        accHi += inv * tHi;
    }

    float acc[NCLS] = {accLo.x, accLo.y, accLo.z, accLo.w,
                       accHi.x, accHi.y, accHi.z, accHi.w};
    #pragma unroll
    for (int c = 0; c < NCLS; ++c) {
        acc[c] += __shfl_xor(acc[c], 1);
        acc[c] += __shfl_xor(acc[c], 2);
        acc[c] += __shfl_xor(acc[c], 4);
    }

    if (q == 0) {
        const vh8* h8 = reinterpret_cast<const vh8*>(h + (size_t)d * HID);
        vh8 m0 = h8[0];
        vh8 m1 = h8[1];
        float hv[HID];
        #pragma unroll
        for (int i = 0; i < 8; ++i) { hv[i] = (float)m0[i]; hv[i + 8] = (float)m1[i]; }
        #pragma unroll
        for (int i = 0; i < HID; ++i) {
            #pragma unroll
            for (int c = 0; c < NCLS; ++c)
                acc[c] += hv[i] * root2[i * NCLS + c];
        }
        #pragma unroll
        for (int c = 0; c < NCLS; ++c) acc[c] += bias2[c];
        float4* o4 = reinterpret_cast<float4*>(out + (size_t)d * NCLS);
        o4[0] = make_float4(acc[0], acc[1], acc[2], acc[3]);
        o4[1] = make_float4(acc[4], acc[5], acc[6], acc[7]);
    }
}

// ---------------- launch ----------------

extern "C" void kernel_launch(void* const* d_in, const int* in_sizes, int n_in,
                              void* d_out, int out_size, void* d_ws, size_t ws_size,
                              hipStream_t stream) {
    const int*   edge_index = (const int*)  d_in[0];
    const int*   edge_type  = (const int*)  d_in[1];
    const float* basis1     = (const float*)d_in[2];
    const float* comp1      = (const float*)d_in[3];
    const float* root1      = (const float*)d_in[4];
    const float* bias1      = (const float*)d_in[5];
    const float* basis2     = (const float*)d_in[6];
    const float* comp2      = (const float*)d_in[7];
    const float* root2      = (const float*)d_in[8];
    const float* bias2      = (const float*)d_in[9];
    float* out = (float*)d_out;

    const int E = in_sizes[1];
    const int N = in_sizes[4] / HID;
    const int nbuk = (N + BWID - 1) >> SHIFT;
    const int* src = edge_index;
    const int* dst = edge_index + E;

    char* base = (char*)d_ws;
    size_t off = 0;
    auto alloc = [&](size_t bytes, size_t align) -> char* {
        off = (off + align - 1) & ~(align - 1);
        char* p = base + off;
        off += bytes;
        return p;
    };
    // contiguous zero region: hs | hd
    int*  hs       = (int*)  alloc((size_t)NBUKMAX * 4, 4);
    int*  hd       = (int*)  alloc((size_t)NBUKMAX * 4, 4);
    int*  gcs      = (int*)  alloc((size_t)NBUKMAX * 4, 4);
    int*  gcd      = (int*)  alloc((size_t)NBUKMAX * 4, 4);
    int*  bases_s  = (int*)  alloc((size_t)(NBUKMAX + 1) * 4, 4);
    int*  based    = (int*)  alloc((size_t)(NBUKMAX + 1) * 4, 4);
    int*  rowptr   = (int*)  alloc((size_t)(N + 1) * 4, 4);
    int*  rowptr_s = (int*)  alloc((size_t)(N + 1) * 4, 4);
    float* w2      = (float*)alloc((size_t)NREL * HID * NCLS * 4, 16);
    _Float16* h    = (_Float16*)alloc((size_t)N * HID * 2, 16);
    float* sinv    = (float*)alloc((size_t)E * 4, 4);
    int*  Ax0      = (int*)  alloc((size_t)E * 4, 4);
    int*  Ad0      = (int*)  alloc((size_t)E * 4, 4);
    int*  Ax       = (int*)  alloc((size_t)E * 4, 16);
    int*  Ad       = (int*)  alloc((size_t)E * 4, 4);
    int2* B        = (int2*) alloc((size_t)E * 8, 8);
    int2* e2       = (int2*) alloc((size_t)E * 8, 8);
    _Float16* msg  = (_Float16*)alloc((size_t)E * HID * 2, 16);

    hipMemsetAsync(hs, 0, (size_t)NBUKMAX * 2 * 4, stream);

    {   int M = NREL * HID * NCLS;
        compute_w2_kernel<<<(M + 255) / 256, 256, 0, stream>>>(comp2, basis2, w2);
    }
    ghist_kernel<<<2048, 256, 0, stream>>>(src, dst, hs, hd, E, nbuk);
    scanbuk_kernel<<<1, 256, 0, stream>>>(hs, hd, gcs, bases_s, based, gcd, nbuk, E);

    int nblk = (E + TILE - 1) / TILE;
    pass1_kernel<<<nblk, 256, 0, stream>>>(src, dst, edge_type, gcs, Ax0, Ad0, E);
    pass1b_kernel<<<nbuk, 512, 0, stream>>>(Ax0, Ad0, bases_s, Ax, Ad, rowptr_s, N, E);
    pass2_kernel<<<nblk, 256, 0, stream>>>(Ax, Ad, gcd, B, E);
    pass3_kernel<<<nbuk, 512, 0, stream>>>(B, based, e2, rowptr, N, E);

    {   int blocks = (int)((N + 15) / 16);
        layer1A_node_kernel<<<blocks, 256, 0, stream>>>(
            Ax, rowptr_s, comp1, basis1, msg, N);
    }
    {   long total = (long)N * 8;
        layer1B_kernel<<<(int)((total + 255) / 256), 256, 0, stream>>>(
            e2, rowptr, msg, root1, bias1, h, sinv, N);
    }
    {   long total = (long)N * 8;
        layer2_kernel<<<(int)((total + 255) / 256), 256, 0, stream>>>(
            e2, rowptr, sinv, w2, h, root2, bias2, out, N);
    }
}

// Round 23
// 349.117 us; speedup vs baseline: 1.1654x; 1.0092x over previous
//
#include <hip/hip_runtime.h>

#define NREL   50
#define NBASE  30
#define HID    16
#define NCLS   8

#define SHIFT   8
#define BWID    (1 << SHIFT)       // 256 nodes per bucket
#define NBUKMAX 512                // supports N <= 131072 at SHIFT=8
#define TILE    4096               // edges per scatter block
#define EPB     16                 // edges per thread (256 threads)
#define W2P     132                // padded w2 row (floats), 528B 16B-aligned
#define C1P     36                 // padded comp1 row (floats; 144B rotates banks)

typedef float    vf4 __attribute__((ext_vector_type(4)));
typedef _Float16 vh8 __attribute__((ext_vector_type(8)));

// ---------------- setup ----------------

__global__ void compute_w2_kernel(const float* __restrict__ comp2,
                                  const float* __restrict__ basis2,
                                  float* __restrict__ w2) {
    int i = blockIdx.x * blockDim.x + threadIdx.x;
    if (i >= NREL * HID * NCLS) return;
    int r  = i / (HID * NCLS);
    int hc = i % (HID * NCLS);
    float acc = 0.f;
    #pragma unroll
    for (int b = 0; b < NBASE; ++b)
        acc += comp2[r * NBASE + b] * basis2[b * HID * NCLS + hc];
    w2[i] = acc;
}

// ---------------- bucket histograms (LDS-privatized) ----------------

__global__ void ghist_kernel(const int* __restrict__ src,
                             const int* __restrict__ dst,
                             int* __restrict__ hs, int* __restrict__ hd,
                             int E, int nbuk) {
    __shared__ int lhs[NBUKMAX], lhd[NBUKMAX];
    for (int j = threadIdx.x; j < nbuk; j += blockDim.x) { lhs[j] = 0; lhd[j] = 0; }
    __syncthreads();
    for (long e = (long)blockIdx.x * blockDim.x + threadIdx.x; e < E;
         e += (long)gridDim.x * blockDim.x) {
        atomicAdd(&lhs[src[e] >> SHIFT], 1);
        atomicAdd(&lhd[dst[e] >> SHIFT], 1);
    }
    __syncthreads();
    for (int j = threadIdx.x; j < nbuk; j += blockDim.x) {
        if (lhs[j]) atomicAdd(&hs[j], lhs[j]);
        if (lhd[j]) atomicAdd(&hd[j], lhd[j]);
    }
}

// exclusive scans of both histograms; keeps pristine bases for pass1b/pass3
__global__ void scanbuk_kernel(const int* __restrict__ hs, const int* __restrict__ hd,
                               int* __restrict__ gcs, int* __restrict__ bases_s,
                               int* __restrict__ based, int* __restrict__ gcd,
                               int nbuk, int E) {
    __shared__ int a[NBUKMAX], b[NBUKMAX];
    int tid = threadIdx.x;
    for (int j = tid; j < nbuk; j += blockDim.x) { a[j] = hs[j]; b[j] = hd[j]; }
    __syncthreads();
    if (tid == 0) {
        int run = 0;
        for (int i = 0; i < nbuk; ++i) { int v = a[i]; a[i] = run; run += v; }
        run = 0;
        for (int i = 0; i < nbuk; ++i) { int v = b[i]; b[i] = run; run += v; }
    }
    __syncthreads();
    for (int j = tid; j < nbuk; j += blockDim.x) {
        gcs[j] = a[j]; bases_s[j] = a[j];
        based[j] = b[j]; gcd[j] = b[j];
    }
    if (tid == 0) { bases_s[nbuk] = E; based[nbuk] = E; }
}

// ---------------- pass 1: coarse bucket-sort by src>>SHIFT ----------------
// fused record write: Axd0[pos] = {s|t<<17, d}
__global__ void pass1_kernel(const int* __restrict__ src,
                             const int* __restrict__ dst,
                             const int* __restrict__ et,
                             int* __restrict__ gcur,
                             int2* __restrict__ Axd0, int E) {
    __shared__ int lhist[NBUKMAX], lbase[NBUKMAX], lcur[NBUKMAX];
    int tid = threadIdx.x;
    for (int j = tid; j < NBUKMAX; j += 256) { lhist[j] = 0; lcur[j] = 0; }
    __syncthreads();
    int px[EPB], pd[EPB]; int bk[EPB];
    long e0 = (long)blockIdx.x * TILE;
    #pragma unroll
    for (int j = 0; j < EPB; ++j) {
        long e = e0 + j * 256 + tid;
        if (e < E) {
            int s = src[e], d = dst[e], t = et[e];
            px[j] = s | (t << 17);
            pd[j] = d;
            bk[j] = s >> SHIFT;
            atomicAdd(&lhist[bk[j]], 1);
        } else bk[j] = -1;
    }
    __syncthreads();
    for (int j = tid; j < NBUKMAX; j += 256)
        if (lhist[j] > 0) lbase[j] = atomicAdd(&gcur[j], lhist[j]);
    __syncthreads();
    #pragma unroll
    for (int j = 0; j < EPB; ++j) {
        if (bk[j] >= 0) {
            int r = atomicAdd(&lcur[bk[j]], 1);
            Axd0[lbase[bk[j]] + r] = make_int2(px[j], pd[j]);
        }
    }
}

// ---------------- pass 1b: exact src grouping within each bucket (512 threads) ----------------
__global__ void pass1b_kernel(const int2* __restrict__ Axd0,
                              const int* __restrict__ bases_s,
                              int* __restrict__ Ax, int* __restrict__ Ad,
                              int* __restrict__ rowptr_s, int N, int E) {
    __shared__ int lh[BWID], sA[BWID], sB[BWID];
    int blk = blockIdx.x, tid = threadIdx.x;
    int nt = blockDim.x;
    int k0 = bases_s[blk], k1 = bases_s[blk + 1], cnt = k1 - k0;
    for (int j = tid; j < BWID; j += nt) lh[j] = 0;
    __syncthreads();
    for (int i = tid; i < cnt; i += nt) {
        int slow = Axd0[k0 + i].x & (BWID - 1);
        atomicAdd(&lh[slow], 1);
    }
    __syncthreads();
    for (int j = tid; j < BWID; j += nt) sA[j] = lh[j];
    __syncthreads();
    int* cur = sA; int* oth = sB;
    for (int off = 1; off < BWID; off <<= 1) {
        for (int j = tid; j < BWID; j += nt)
            oth[j] = cur[j] + (j >= off ? cur[j - off] : 0);
        __syncthreads();
        int* t_ = cur; cur = oth; oth = t_;
    }
    for (int j = tid; j < BWID; j += nt) {
        int excl = cur[j] - lh[j];
        oth[j] = excl;
        int s = blk * BWID + j;
        if (s < N) rowptr_s[s] = k0 + excl;
    }
    __syncthreads();
    for (int i = tid; i < cnt; i += nt) {
        int2 xd = Axd0[k0 + i];
        int slow = xd.x & (BWID - 1);
        int pos = k0 + atomicAdd(&oth[slow], 1);
        Ax[pos] = xd.x;
        Ad[pos] = xd.y;
    }
    if (blk == 0 && tid == 0) rowptr_s[N] = E;
}

// ---------------- pass 2: bucket-sort by dst>>SHIFT ----------------
// B[pos] = {s|t<<17, psi | dlow<<21}, psi = index into Ax (= msg row).
__global__ void pass2_kernel(const int* __restrict__ Ax,
                             const int* __restrict__ Ad,
                             int* __restrict__ gcur, int2* __restrict__ B, int E) {
    __shared__ int lhist[NBUKMAX], lbase[NBUKMAX], lcur[NBUKMAX];
    int tid = threadIdx.x;
    for (int j = tid; j < NBUKMAX; j += 256) { lhist[j] = 0; lcur[j] = 0; }
    __syncthreads();
    int2 p[EPB]; int bk[EPB];
    long e0 = (long)blockIdx.x * TILE;
    #pragma unroll
    for (int j = 0; j < EPB; ++j) {
        long e = e0 + j * 256 + tid;
        if (e < E) {
            int x = Ax[e];
            int d = Ad[e];
            p[j] = make_int2(x, (int)e | ((d & (BWID - 1)) << 21));
            bk[j] = d >> SHIFT;
            atomicAdd(&lhist[bk[j]], 1);
        } else bk[j] = -1;
    }
    __syncthreads();
    for (int j = tid; j < NBUKMAX; j += 256)
        if (lhist[j] > 0) lbase[j] = atomicAdd(&gcur[j], lhist[j]);
    __syncthreads();
    #pragma unroll
    for (int j = 0; j < EPB; ++j) {
        if (bk[j] >= 0) {
            int r = atomicAdd(&lcur[bk[j]], 1);
            B[lbase[bk[j]] + r] = p[j];
        }
    }
}

// ---------------- pass 3: exact dst grouping (512 threads); split e2x/psi ----------------
__global__ void pass3_kernel(const int2* __restrict__ B,
                             const int* __restrict__ based,
                             int* __restrict__ e2x, int* __restrict__ psi,
                             int* __restrict__ rowptr, int N, int E) {
    __shared__ int lh[BWID], sA[BWID], sB[BWID];
    int blk = blockIdx.x, tid = threadIdx.x;
    int nt = blockDim.x;
    int k0 = based[blk], k1 = based[blk + 1], cnt = k1 - k0;
    for (int j = tid; j < BWID; j += nt) lh[j] = 0;
    __syncthreads();
    for (int i = tid; i < cnt; i += nt) {
        int dlow = ((unsigned)B[k0 + i].y) >> 21;
        atomicAdd(&lh[dlow], 1);
    }
    __syncthreads();
    for (int j = tid; j < BWID; j += nt) sA[j] = lh[j];
    __syncthreads();
    int* cur = sA; int* oth = sB;
    for (int off = 1; off < BWID; off <<= 1) {
        for (int j = tid; j < BWID; j += nt)
            oth[j] = cur[j] + (j >= off ? cur[j - off] : 0);
        __syncthreads();
        int* t_ = cur; cur = oth; oth = t_;
    }
    for (int j = tid; j < BWID; j += nt) {
        int excl = cur[j] - lh[j];
        oth[j] = excl;
        int d = blk * BWID + j;
        if (d < N) rowptr[d] = k0 + excl;
    }
    __syncthreads();
    for (int i = tid; i < cnt; i += nt) {
        int2 b = B[k0 + i];
        int dlow = ((unsigned)b.y) >> 21;
        int pos = k0 + atomicAdd(&oth[dlow], 1);
        e2x[pos] = b.x;
        psi[pos] = b.y & 0x1FFFFF;
    }
    if (blk == 0 && tid == 0) rowptr[N] = E;
}

// ---------------- layer 1 phase A: node-centric, pipelined 4-edge ILP, fp16 msg ----------------
__global__ void layer1A_node_kernel(const int* __restrict__ Ax,
                                    const int* __restrict__ rowptr_s,
                                    const float* __restrict__ comp1,
                                    const float* __restrict__ basis1,
                                    _Float16* __restrict__ msg, int N) {
    __shared__ float c1s[NREL * C1P];
    for (int i = threadIdx.x; i < NREL * C1P; i += blockDim.x) {
        int t = i / C1P, b = i % C1P;
        c1s[i] = (b < NBASE) ? comp1[t * NBASE + b] : 0.f;
    }
    __syncthreads();
    int gid = threadIdx.x >> 4;
    int l   = threadIdx.x & 15;
    int s = blockIdx.x * 16 + gid;
    if (s >= N) return;
    int k0 = rowptr_s[s], k1 = rowptr_s[s + 1];
    if (k0 == k1) return;

    vf4 b4[8];
    {
        long stride = (long)N * HID;
        const float* bp = basis1 + (long)s * HID + l;
        float breg[32];
        #pragma unroll
        for (int b = 0; b < NBASE; ++b)
            breg[b] = bp[(long)b * stride];
        #pragma unroll
        for (int b = NBASE; b < 32; ++b) breg[b] = 0.f;
        #pragma unroll
        for (int i = 0; i < 8; ++i)
            b4[i] = (vf4){breg[4*i], breg[4*i+1], breg[4*i+2], breg[4*i+3]};
    }

    int k = k0;
    if (k + 4 <= k1) {
        int c0x = Ax[k + 0], c1x = Ax[k + 1], c2x = Ax[k + 2], c3x = Ax[k + 3];
        for (;;) {
            bool more = (k + 8 <= k1);
            int n0, n1, n2, n3;
            if (more) {
                n0 = Ax[k + 4]; n1 = Ax[k + 5]; n2 = Ax[k + 6]; n3 = Ax[k + 7];
            }
            const vf4* c0 = reinterpret_cast<const vf4*>(c1s + (((unsigned)c0x) >> 17) * C1P);
            const vf4* c1 = reinterpret_cast<const vf4*>(c1s + (((unsigned)c1x) >> 17) * C1P);
            const vf4* c2 = reinterpret_cast<const vf4*>(c1s + (((unsigned)c2x) >> 17) * C1P);
            const vf4* c3 = reinterpret_cast<const vf4*>(c1s + (((unsigned)c3x) >> 17) * C1P);
            vf4 a0 = {0.f,0.f,0.f,0.f}, a1 = a0, a2 = a0, a3 = a0;
            #pragma unroll
            for (int i = 0; i < 8; ++i) {
                a0 += c0[i] * b4[i];
                a1 += c1[i] * b4[i];
                a2 += c2[i] * b4[i];
                a3 += c3[i] * b4[i];
            }
            float r0 = (a0.x + a0.y) + (a0.z + a0.w);
            float r1 = (a1.x + a1.y) + (a1.z + a1.w);
            float r2 = (a2.x + a2.y) + (a2.z + a2.w);
            float r3 = (a3.x + a3.y) + (a3.z + a3.w);
            __builtin_nontemporal_store((_Float16)r0, &msg[(long)(k + 0) * HID + l]);
            __builtin_nontemporal_store((_Float16)r1, &msg[(long)(k + 1) * HID + l]);
            __builtin_nontemporal_store((_Float16)r2, &msg[(long)(k + 2) * HID + l]);
            __builtin_nontemporal_store((_Float16)r3, &msg[(long)(k + 3) * HID + l]);
            k += 4;
            if (!more) break;
            c0x = n0; c1x = n1; c2x = n2; c3x = n3;
        }
    }
    for (; k < k1; ++k) {
        int t = ((unsigned)Ax[k]) >> 17;
        const vf4* cr4 = reinterpret_cast<const vf4*>(c1s + t * C1P);
        vf4 acc4 = {0.f, 0.f, 0.f, 0.f};
        #pragma unroll
        for (int i = 0; i < 8; ++i)
            acc4 += cr4[i] * b4[i];
        float acc = (acc4.x + acc4.y) + (acc4.z + acc4.w);
        __builtin_nontemporal_store((_Float16)acc, &msg[(long)k * HID + l]);
    }
}

// ---------------- layer 1 phase B: 8 threads per dst node, fp16 msg gather, fp16 h out ----------------
__global__ void layer1B_kernel(const int* __restrict__ e2x,
                               const int* __restrict__ psi,
                               const int* __restrict__ rowptr,
                               const _Float16* __restrict__ msg,
                               const float* __restrict__ root1,
                               const float* __restrict__ bias1,
                               _Float16* __restrict__ h, float* __restrict__ sinv, int N) {
    long gid = (long)blockIdx.x * blockDim.x + threadIdx.x;
    int d = (int)(gid >> 3);
    if (d >= N) return;
    int q = (int)(gid & 7);
    int k0 = rowptr[d], k1 = rowptr[d + 1];

    float acc[HID];
    #pragma unroll
    for (int i = 0; i < HID; ++i) acc[i] = 0.f;

    for (int k = k0 + q; k < k1; k += 8) {
        unsigned t = ((unsigned)e2x[k]) >> 17;
        int c = 0;
        for (int j = k0; j < k1; ++j)
            c += ((((unsigned)e2x[j]) >> 17) == t);
        float inv = 1.0f / (float)c;
        sinv[k] = inv;
        const vh8* m8 = reinterpret_cast<const vh8*>(msg + (long)psi[k] * HID);
        vh8 m0 = __builtin_nontemporal_load(m8);
        vh8 m1 = __builtin_nontemporal_load(m8 + 1);
        #pragma unroll
        for (int i = 0; i < 8; ++i) {
            acc[i]     += inv * (float)m0[i];
            acc[i + 8] += inv * (float)m1[i];
        }
    }

    #pragma unroll
    for (int i = 0; i < HID; ++i) {
        acc[i] += __shfl_xor(acc[i], 1);
        acc[i] += __shfl_xor(acc[i], 2);
        acc[i] += __shfl_xor(acc[i], 4);
    }

    if (q == 0) {
        const float4* r4 = reinterpret_cast<const float4*>(root1 + (size_t)d * HID);
        vh8 o0, o1;
        #pragma unroll
        for (int p = 0; p < 2; ++p) {
            float4 ra = r4[2 * p], rb = r4[2 * p + 1];
            float rv[8] = {ra.x, ra.y, ra.z, ra.w, rb.x, rb.y, rb.z, rb.w};
            #pragma unroll
            for (int i = 0; i < 8; ++i) {
                float v = acc[p * 8 + i] + rv[i] + bias1[p * 8 + i];
                if (p == 0) o0[i] = (_Float16)v; else o1[i] = (_Float16)v;
            }
        }
        vh8* h8 = reinterpret_cast<vh8*>(h + (size_t)d * HID);
        h8[0] = o0;
        h8[1] = o1;
    }
}

// ---------------- layer 2: 8 threads per dst node (k-split), fp16 h, [t][hc] w2 LDS ----------------
__global__ void layer2_kernel(const int* __restrict__ e2x,
                              const int* __restrict__ rowptr,
                              const float* __restrict__ sinv,
                              const float* __restrict__ w2,
                              const _Float16* __restrict__ h,
                              const float* __restrict__ root2,
                              const float* __restrict__ bias2,
                              float* __restrict__ out, int N) {
    __shared__ __align__(16) float w2s[NREL * W2P];    // [t][hc], 26.4 KB
    for (int i = threadIdx.x; i < NREL * HID * NCLS; i += blockDim.x) {
        int t = i / (HID * NCLS);
        int hc = i % (HID * NCLS);
        w2s[t * W2P + hc] = w2[i];
    }
    __syncthreads();

    long gid = (long)blockIdx.x * blockDim.x + threadIdx.x;
    int d = (int)(gid >> 3);
    if (d >= N) return;
    int q = (int)(gid & 7);
    int k0 = rowptr[d], k1 = rowptr[d + 1];

    vf4 accLo = {0.f,0.f,0.f,0.f}, accHi = {0.f,0.f,0.f,0.f};

    for (int k = k0 + q; k < k1; k += 8) {
        int v = e2x[k];
        int s = v & 0x1FFFF;
        int t = ((unsigned)v) >> 17;
        float inv = sinv[k];
        const vh8* h8 = reinterpret_cast<const vh8*>(h + (size_t)s * HID);
        vh8 m0 = h8[0];
        vh8 m1 = h8[1];
        float hv[HID];
        #pragma unroll
        for (int i = 0; i < 8; ++i) { hv[i] = (float)m0[i]; hv[i + 8] = (float)m1[i]; }
        const vf4* wp = reinterpret_cast<const vf4*>(w2s + t * W2P);
        vf4 tLo = {0.f,0.f,0.f,0.f}, tHi = {0.f,0.f,0.f,0.f};
        #pragma unroll
        for (int i = 0; i < HID; ++i) {
            tLo += hv[i] * wp[2 * i];
            tHi += hv[i] * wp[2 * i + 1];
        }
        accLo += inv * tLo;
        accHi += inv * tHi;
    }

    float acc[NCLS] = {accLo.x, accLo.y, accLo.z, accLo.w,
                       accHi.x, accHi.y, accHi.z, accHi.w};
    #pragma unroll
    for (int c = 0; c < NCLS; ++c) {
        acc[c] += __shfl_xor(acc[c], 1);
        acc[c] += __shfl_xor(acc[c], 2);
        acc[c] += __shfl_xor(acc[c], 4);
    }

    if (q == 0) {
        const vh8* h8 = reinterpret_cast<const vh8*>(h + (size_t)d * HID);
        vh8 m0 = h8[0];
        vh8 m1 = h8[1];
        float hv[HID];
        #pragma unroll
        for (int i = 0; i < 8; ++i) { hv[i] = (float)m0[i]; hv[i + 8] = (float)m1[i]; }
        #pragma unroll
        for (int i = 0; i < HID; ++i) {
            #pragma unroll
            for (int c = 0; c < NCLS; ++c)
                acc[c] += hv[i] * root2[i * NCLS + c];
        }
        #pragma unroll
        for (int c = 0; c < NCLS; ++c) acc[c] += bias2[c];
        float4* o4 = reinterpret_cast<float4*>(out + (size_t)d * NCLS);
        o4[0] = make_float4(acc[0], acc[1], acc[2], acc[3]);
        o4[1] = make_float4(acc[4], acc[5], acc[6], acc[7]);
    }
}

// ---------------- launch ----------------

extern "C" void kernel_launch(void* const* d_in, const int* in_sizes, int n_in,
                              void* d_out, int out_size, void* d_ws, size_t ws_size,
                              hipStream_t stream) {
    const int*   edge_index = (const int*)  d_in[0];
    const int*   edge_type  = (const int*)  d_in[1];
    const float* basis1     = (const float*)d_in[2];
    const float* comp1      = (const float*)d_in[3];
    const float* root1      = (const float*)d_in[4];
    const float* bias1      = (const float*)d_in[5];
    const float* basis2     = (const float*)d_in[6];
    const float* comp2      = (const float*)d_in[7];
    const float* root2      = (const float*)d_in[8];
    const float* bias2      = (const float*)d_in[9];
    float* out = (float*)d_out;

    const int E = in_sizes[1];
    const int N = in_sizes[4] / HID;
    const int nbuk = (N + BWID - 1) >> SHIFT;
    const int* src = edge_index;
    const int* dst = edge_index + E;

    char* base = (char*)d_ws;
    size_t off = 0;
    auto alloc = [&](size_t bytes, size_t align) -> char* {
        off = (off + align - 1) & ~(align - 1);
        char* p = base + off;
        off += bytes;
        return p;
    };
    // contiguous zero region: hs | hd
    int*  hs       = (int*)  alloc((size_t)NBUKMAX * 4, 4);
    int*  hd       = (int*)  alloc((size_t)NBUKMAX * 4, 4);
    int*  gcs      = (int*)  alloc((size_t)NBUKMAX * 4, 4);
    int*  gcd      = (int*)  alloc((size_t)NBUKMAX * 4, 4);
    int*  bases_s  = (int*)  alloc((size_t)(NBUKMAX + 1) * 4, 4);
    int*  based    = (int*)  alloc((size_t)(NBUKMAX + 1) * 4, 4);
    int*  rowptr   = (int*)  alloc((size_t)(N + 1) * 4, 4);
    int*  rowptr_s = (int*)  alloc((size_t)(N + 1) * 4, 4);
    float* w2      = (float*)alloc((size_t)NREL * HID * NCLS * 4, 16);
    _Float16* h    = (_Float16*)alloc((size_t)N * HID * 2, 16);
    float* sinv    = (float*)alloc((size_t)E * 4, 4);
    int2* Axd0     = (int2*) alloc((size_t)E * 8, 8);
    int*  Ax       = (int*)  alloc((size_t)E * 4, 16);
    int*  Ad       = (int*)  alloc((size_t)E * 4, 4);
    int2* B        = (int2*) alloc((size_t)E * 8, 8);
    int*  e2x      = (int*)  alloc((size_t)E * 4, 4);
    int*  psi      = (int*)  alloc((size_t)E * 4, 4);
    _Float16* msg  = (_Float16*)alloc((size_t)E * HID * 2, 16);

    hipMemsetAsync(hs, 0, (size_t)NBUKMAX * 2 * 4, stream);

    {   int M = NREL * HID * NCLS;
        compute_w2_kernel<<<(M + 255) / 256, 256, 0, stream>>>(comp2, basis2, w2);
    }
    ghist_kernel<<<2048, 256, 0, stream>>>(src, dst, hs, hd, E, nbuk);
    scanbuk_kernel<<<1, 256, 0, stream>>>(hs, hd, gcs, bases_s, based, gcd, nbuk, E);

    int nblk = (E + TILE - 1) / TILE;
    pass1_kernel<<<nblk, 256, 0, stream>>>(src, dst, edge_type, gcs, Axd0, E);
    pass1b_kernel<<<nbuk, 512, 0, stream>>>(Axd0, bases_s, Ax, Ad, rowptr_s, N, E);
    pass2_kernel<<<nblk, 256, 0, stream>>>(Ax, Ad, gcd, B, E);
    pass3_kernel<<<nbuk, 512, 0, stream>>>(B, based, e2x, psi, rowptr, N, E);

    {   int blocks = (int)((N + 15) / 16);
        layer1A_node_kernel<<<blocks, 256, 0, stream>>>(
            Ax, rowptr_s, comp1, basis1, msg, N);
    }
    {   long total = (long)N * 8;
        layer1B_kernel<<<(int)((total + 255) / 256), 256, 0, stream>>>(
            e2x, psi, rowptr, msg, root1, bias1, h, sinv, N);
    }
    {   long total = (long)N * 8;
        layer2_kernel<<<(int)((total + 255) / 256), 256, 0, stream>>>(
            e2x, rowptr, sinv, w2, h, root2, bias2, out, N);
    }
}